// Round 20
// baseline (152.686 us; speedup 1.0000x reference)
//
#include <hip/hip_runtime.h>

typedef short bf16x8 __attribute__((ext_vector_type(8)));
typedef float f32x4 __attribute__((ext_vector_type(4)));

#define ATT_SCALE 0.17677669529663687f

__device__ __forceinline__ unsigned short f2b(float f) {
    unsigned int u = __builtin_bit_cast(unsigned int, f);
    unsigned int r = u + 0x7FFFu + ((u >> 16) & 1u);
    return (unsigned short)(r >> 16);
}
__device__ __forceinline__ float b2f(unsigned short v) {
    return __builtin_bit_cast(float, (unsigned int)v << 16);
}
__device__ __forceinline__ float wsum64(float v) {
    #pragma unroll
    for (int m = 32; m; m >>= 1) v += __shfl_xor(v, m, 64);
    return v;
}

// WF fragment offsets (ushorts): Wq 0, Wv 65536, Wro 131072, Wg2 196608,
// Wp 262144, Wo 278528, WgeLo 344064, WgeHi 409600. total 475136.

// ---------------------------------------------------------------------------
// K_setup: all parallel prep. grid 2496 x 256.
__global__ __launch_bounds__(256) void k_setup(const float* __restrict__ w1,
                                               const float* __restrict__ wqkv,
                                               const float* __restrict__ b1,
                                               const float* __restrict__ bqkv,
                                               const float* __restrict__ gate_road_w,
                                               const float* __restrict__ ext_proj_w,
                                               const float* __restrict__ ext_qkv_w,
                                               const float* __restrict__ road_out_w,
                                               const float* __restrict__ ext_out_w,
                                               const float* __restrict__ gate_ext_w,
                                               const float* __restrict__ low,
                                               unsigned short* __restrict__ W3b,
                                               unsigned short* __restrict__ Wcb,
                                               unsigned short* __restrict__ WF,
                                               float* __restrict__ bcv,
                                               float* __restrict__ mean_low) {
    int bid = blockIdx.x, t = threadIdx.x;
    __shared__ float sel[8][256];
    __shared__ float red[8][4];
    if (bid >= 448) {
        int bc = bid - 448;
        const f32x4* p4 = (const f32x4*)(low + (size_t)bc * 4096);
        float s = 0.f;
        for (int i = t; i < 1024; i += 256) {
            f32x4 v = p4[i];
            s += v[0] + v[1] + v[2] + v[3];
        }
        s = wsum64(s);
        if ((t & 63) == 0) red[0][t >> 6] = s;
        __syncthreads();
        if (t == 0) mean_low[bc] = (red[0][0] + red[0][1] + red[0][2] + red[0][3]) * (1.0f / 4096.0f);
    } else if (bid < 256) {
        int i = bid * 256 + t;
        int o = i >> 8, k = i & 255;
        W3b[i] = f2b(gate_road_w[o * 512 + k]);
    } else if (bid < 320) {
        int o0 = (bid - 256) * 8;
        #pragma unroll
        for (int r = 0; r < 8; r++) {
            int o = o0 + r;
            int c = (o < 256) ? o : o - 256;
            int g = (o < 256) ? 1 : 2;
            sel[r][t] = wqkv[(size_t)(3 * c + g) * 256 + t];
        }
        __syncthreads();
        float b1v = b1[t];
        #pragma unroll
        for (int r = 0; r < 8; r++) {
            float v = wsum64(sel[r][t] * b1v);
            if ((t & 63) == 0) red[r][t >> 6] = v;
        }
        __syncthreads();
        if (t < 8) {
            int o = o0 + t;
            int c = (o < 256) ? o : o - 256;
            int g = (o < 256) ? 1 : 2;
            bcv[o] = red[t][0] + red[t][1] + red[t][2] + red[t][3] + bqkv[3 * c + g];
        }
        float acc[8] = {};
        #pragma unroll 16
        for (int m = 0; m < 256; m++) {
            float w1v = w1[(size_t)m * 256 + t];
            #pragma unroll
            for (int r = 0; r < 8; r++) acc[r] += sel[r][m] * w1v;
        }
        #pragma unroll
        for (int r = 0; r < 8; r++) Wcb[(size_t)(o0 + r) * 256 + t] = f2b(acc[r]);
    } else {
        int mb = bid - 320;
        int m = mb >> 4, ctile = mb & 15;
        const float* src;
        int stride, K, coff;
        unsigned short* dst;
        switch (m) {
        case 0: src = ext_qkv_w;                     stride = 256; K = 256; coff = 0;   dst = WF;          break;
        case 1: src = ext_qkv_w + (size_t)512 * 256; stride = 256; K = 256; coff = 0;   dst = WF + 65536;  break;
        case 2: src = road_out_w;                    stride = 256; K = 256; coff = 0;   dst = WF + 131072; break;
        case 3: src = gate_road_w;                   stride = 512; K = 256; coff = 256; dst = WF + 196608; break;
        case 4: src = ext_proj_w;                    stride = 64;  K = 64;  coff = 0;   dst = WF + 262144; break;
        case 5: src = ext_out_w;                     stride = 256; K = 256; coff = 0;   dst = WF + 278528; break;
        case 6: src = gate_ext_w;                    stride = 512; K = 256; coff = 0;   dst = WF + 344064; break;
        default: src = gate_ext_w;                   stride = 512; K = 256; coff = 256; dst = WF + 409600; break;
        }
        int lc = t >> 4, kseg = t & 15;
        int k0 = kseg * 16;
        if (k0 < K) {
            int c = ctile * 16 + lc;
            const float* sp = src + (size_t)c * stride + coff + k0;
            f32x4 v0 = *(const f32x4*)sp;
            f32x4 v1 = *(const f32x4*)(sp + 4);
            f32x4 v2 = *(const f32x4*)(sp + 8);
            f32x4 v3 = *(const f32x4*)(sp + 12);
            int kk = kseg >> 1;
            int Kt = K >> 5;
            #pragma unroll
            for (int h = 0; h < 2; h++) {
                int lhi = (kseg & 1) * 2 + h;
                int lane = lhi * 16 + lc;
                bf16x8 o;
                f32x4 a = h ? v2 : v0, b = h ? v3 : v1;
                #pragma unroll
                for (int i = 0; i < 4; i++) { o[i] = (short)f2b(a[i]); o[4 + i] = (short)f2b(b[i]); }
                *(bf16x8*)(dst + ((size_t)(ctile * Kt + kk) << 9) + lane * 8) = o;
            }
        }
    }
}

// ---------------------------------------------------------------------------
// K_tiny: 4-hop vector chain via MFMA, 1 block x 256.
__global__ __launch_bounds__(256) void k_tiny(const unsigned short* __restrict__ WF,
                                              const float* __restrict__ ext_context,
                                              const float* __restrict__ ext_proj_b,
                                              const float* __restrict__ ext_qkv_b,
                                              const float* __restrict__ road_out_b,
                                              const float* __restrict__ gate_road_b,
                                              float* __restrict__ ext_q,
                                              float* __restrict__ road_vec,
                                              float* __restrict__ rg_const) {
    __shared__ unsigned short xA[16][264];
    __shared__ unsigned short xB[16][264];
    int t = threadIdx.x;
    int w = t >> 6, lane = t & 63, l15 = lane & 15, lhi = lane >> 4;
    const unsigned short* WqF  = WF;
    const unsigned short* WvF  = WF + 65536;
    const unsigned short* WroF = WF + 131072;
    const unsigned short* WgF  = WF + 196608;
    const unsigned short* WpF  = WF + 262144;
    {
        int b = t >> 5, k0 = (t & 31) * 2;
        float c0v = ext_context[b * 64 + k0];
        float c1v = ext_context[b * 64 + k0 + 1];
        *(unsigned int*)&xA[b][k0] = (unsigned int)f2b(c0v) | ((unsigned int)f2b(c1v) << 16);
    }
    __syncthreads();
    {
        f32x4 acc[4] = {};
        #pragma unroll
        for (int kk = 0; kk < 2; kk++) {
            bf16x8 a = *(const bf16x8*)&xA[l15][kk * 32 + 8 * lhi];
            #pragma unroll
            for (int ni = 0; ni < 4; ni++) {
                int ct = w * 4 + ni;
                bf16x8 bfr = *(const bf16x8*)(WpF + ((size_t)(ct * 2 + kk) << 9) + lane * 8);
                acc[ni] = __builtin_amdgcn_mfma_f32_16x16x32_bf16(a, bfr, acc[ni], 0, 0, 0);
            }
        }
        if (lhi < 2) {
            #pragma unroll
            for (int ni = 0; ni < 4; ni++) {
                int c = w * 64 + ni * 16 + l15;
                float bp = ext_proj_b[c];
                #pragma unroll
                for (int r = 0; r < 4; r++)
                    xB[4 * lhi + r][c] = f2b(acc[ni][r] + bp);
            }
        }
    }
    __syncthreads();
    {
        f32x4 acc[8] = {};
        bool isq = (w < 2);
        int cbase = (w & 1) * 128;
        const unsigned short* Wb = isq ? WqF : WvF;
        for (int kk = 0; kk < 8; kk++) {
            bf16x8 a = *(const bf16x8*)&xB[l15][kk * 32 + 8 * lhi];
            #pragma unroll
            for (int ni = 0; ni < 8; ni++) {
                int ct = (cbase >> 4) + ni;
                bf16x8 bfr = *(const bf16x8*)(Wb + ((size_t)(ct * 8 + kk) << 9) + lane * 8);
                acc[ni] = __builtin_amdgcn_mfma_f32_16x16x32_bf16(a, bfr, acc[ni], 0, 0, 0);
            }
        }
        if (lhi < 2) {
            #pragma unroll
            for (int ni = 0; ni < 8; ni++) {
                int c = cbase + ni * 16 + l15;
                float bb = ext_qkv_b[(isq ? 0 : 512) + c];
                #pragma unroll
                for (int r = 0; r < 4; r++) {
                    int b = 4 * lhi + r;
                    float val = acc[ni][r] + bb;
                    if (isq) ext_q[b * 256 + c] = val;
                    else     xA[b][c] = f2b(val);
                }
            }
        }
    }
    __syncthreads();
    {
        f32x4 acc[4] = {};
        for (int kk = 0; kk < 8; kk++) {
            bf16x8 a = *(const bf16x8*)&xA[l15][kk * 32 + 8 * lhi];
            #pragma unroll
            for (int ni = 0; ni < 4; ni++) {
                int ct = w * 4 + ni;
                bf16x8 bfr = *(const bf16x8*)(WroF + ((size_t)(ct * 8 + kk) << 9) + lane * 8);
                acc[ni] = __builtin_amdgcn_mfma_f32_16x16x32_bf16(a, bfr, acc[ni], 0, 0, 0);
            }
        }
        if (lhi < 2) {
            #pragma unroll
            for (int ni = 0; ni < 4; ni++) {
                int c = w * 64 + ni * 16 + l15;
                float bb = road_out_b[c];
                #pragma unroll
                for (int r = 0; r < 4; r++) {
                    int b = 4 * lhi + r;
                    float val = acc[ni][r] + bb;
                    road_vec[b * 256 + c] = val;
                    xB[b][c] = f2b(val);
                }
            }
        }
    }
    __syncthreads();
    {
        f32x4 acc[4] = {};
        for (int kk = 0; kk < 8; kk++) {
            bf16x8 a = *(const bf16x8*)&xB[l15][kk * 32 + 8 * lhi];
            #pragma unroll
            for (int ni = 0; ni < 4; ni++) {
                int ct = w * 4 + ni;
                bf16x8 bfr = *(const bf16x8*)(WgF + ((size_t)(ct * 8 + kk) << 9) + lane * 8);
                acc[ni] = __builtin_amdgcn_mfma_f32_16x16x32_bf16(a, bfr, acc[ni], 0, 0, 0);
            }
        }
        if (lhi < 2) {
            #pragma unroll
            for (int ni = 0; ni < 4; ni++) {
                int c = w * 64 + ni * 16 + l15;
                float bb = gate_road_b[c];
                #pragma unroll
                for (int r = 0; r < 4; r++)
                    rg_const[(4 * lhi + r) * 256 + c] = acc[ni][r] + bb;
            }
        }
    }
}

// ---------------------------------------------------------------------------
// K_qfold: wq[b,h,:] = sum_d q[b,h,d]*Wc_k[h*32+d,:]  -> fragment-major bf16.
__global__ __launch_bounds__(256) void k_qfold(const unsigned short* __restrict__ Wcb,
                                               const float* __restrict__ bcv,
                                               const float* __restrict__ ext_q,
                                               unsigned short* __restrict__ wqf,
                                               float* __restrict__ cqs) {
    int b = blockIdx.x, t = threadIdx.x;
    __shared__ float qs[256];
    __shared__ float wq[8][256];
    qs[t] = ext_q[b * 256 + t];
    __syncthreads();
    float acc[8] = {};
    #pragma unroll
    for (int h = 0; h < 8; h++)
        #pragma unroll 8
        for (int d = 0; d < 32; d++)
            acc[h] += qs[h * 32 + d] * b2f(Wcb[(size_t)(h * 32 + d) * 256 + t]);
    #pragma unroll
    for (int h = 0; h < 8; h++) wq[h][t] = acc[h];
    if (t < 8) {
        float s = 0.f;
        #pragma unroll 8
        for (int d = 0; d < 32; d++) s += qs[t * 32 + d] * bcv[t * 32 + d];
        cqs[b * 8 + t] = s * ATT_SCALE;
    }
    __syncthreads();
    #pragma unroll
    for (int q2 = 0; q2 < 2; q2++) {
        int idx = t + 256 * q2;
        int kk = idx >> 6, l = idx & 63;
        int row = l & 15;
        int kb = kk * 32 + (l >> 4) * 8;
        bf16x8 o;
        #pragma unroll
        for (int e = 0; e < 8; e++)
            o[e] = (row < 8) ? (short)f2b(wq[row][kb + e]) : (short)0;
        *(bf16x8*)(wqf + ((size_t)(b * 8 + kk) * 64 + l) * 8) = o;
    }
}

// ---------------------------------------------------------------------------
// K_att: folded attention pass. grid 1024 (8b x 128 tiles of 32px), 256 thr.
__global__ __launch_bounds__(256) void k_att(const float* __restrict__ road_feat,
                                             const unsigned short* __restrict__ wqf,
                                             const float* __restrict__ cqs,
                                             float* __restrict__ part) {
    __shared__ __align__(16) char u_smem[32 * 256 * 2];   // 16 KB: Xs, later Yl
    __shared__ unsigned short Xt[256][40];                // [ch][px] bf16
    __shared__ float es_[8][36];
    char* Xc = u_smem;
    float* Yl = (float*)u_smem;
    int bid = blockIdx.x;
    int b  = bid >> 7;
    int p0 = (bid & 127) << 5;
    int t  = threadIdx.x;
    const float* rfb = road_feat + (size_t)b * 1048576;

    int c0 = 2 * (t >> 3);
    int j4 = (t & 7) * 4;
    #pragma unroll
    for (int it = 0; it < 4; ++it) {
        int c = c0 + 64 * it;
        f32x4 g0 = *(const f32x4*)(rfb + (size_t)c * 4096 + p0 + j4);
        f32x4 g1 = *(const f32x4*)(rfb + (size_t)(c + 1) * 4096 + p0 + j4);
        unsigned short h0[4], h1[4];
        #pragma unroll
        for (int i = 0; i < 4; i++) { h0[i] = f2b(g0[i]); h1[i] = f2b(g1[i]); }
        #pragma unroll
        for (int i = 0; i < 4; i++) {
            int j = j4 + i;
            unsigned int pk = (unsigned int)h0[i] | ((unsigned int)h1[i] << 16);
            *(unsigned int*)(Xc + ((j * 512 + 2 * c) ^ ((j & 15) << 4))) = pk;
        }
        *(unsigned int*)&Xt[c][j4]         = (unsigned int)h0[0] | ((unsigned int)h0[1] << 16);
        *(unsigned int*)&Xt[c][j4 + 2]     = (unsigned int)h0[2] | ((unsigned int)h0[3] << 16);
        *(unsigned int*)&Xt[c + 1][j4]     = (unsigned int)h1[0] | ((unsigned int)h1[1] << 16);
        *(unsigned int*)&Xt[c + 1][j4 + 2] = (unsigned int)h1[2] | ((unsigned int)h1[3] << 16);
    }
    __syncthreads();

    int w = t >> 6, lane = t & 63, l15 = lane & 15, lhi = lane >> 4;

    if (w < 2) {
        f32x4 acc = {};
        int px = w * 16 + l15;
        for (int kk = 0; kk < 8; kk++) {
            bf16x8 aq = *(const bf16x8*)(wqf + ((size_t)(b * 8 + kk) * 64 + lane) * 8);
            bf16x8 bx = *(const bf16x8*)(Xc + ((px * 512 + (kk * 32 + 8 * lhi) * 2) ^ ((px & 15) << 4)));
            acc = __builtin_amdgcn_mfma_f32_16x16x32_bf16(aq, bx, acc, 0, 0, 0);
        }
        #pragma unroll
        for (int r = 0; r < 4; r++) {
            int row = 4 * lhi + r;
            if (row < 8)
                es_[row][w * 16 + l15] = expf(acc[r] * ATT_SCALE + cqs[b * 8 + row]);
        }
    }
    __syncthreads();   // Xs reads done; u_smem may now be reused as Yl

    float* pb = part + (size_t)bid * 2056;
    {
        float v = es_[t >> 5][t & 31];
        v += __shfl_xor(v, 1, 64);
        v += __shfl_xor(v, 2, 64);
        v += __shfl_xor(v, 4, 64);
        v += __shfl_xor(v, 8, 64);
        v += __shfl_xor(v, 16, 64);
        if ((lane & 31) == 0) pb[t >> 5] = v;
    }
    bf16x8 besv;
    {
        f32x4 e0 = *(const f32x4*)&es_[l15 & 7][8 * lhi];
        f32x4 e1 = *(const f32x4*)&es_[l15 & 7][8 * lhi + 4];
        #pragma unroll
        for (int i = 0; i < 4; i++) { besv[i] = (short)f2b(e0[i]); besv[4 + i] = (short)f2b(e1[i]); }
    }
    #pragma unroll
    for (int mf = 0; mf < 4; mf++) {
        int f = w * 4 + mf;
        int c = f * 16 + l15;
        bf16x8 ax = *(const bf16x8*)&Xt[c][8 * lhi];
        f32x4 acc = {};
        acc = __builtin_amdgcn_mfma_f32_16x16x32_bf16(ax, besv, acc, 0, 0, 0);
        if (l15 < 8) {
            #pragma unroll
            for (int r = 0; r < 4; r++)
                Yl[(f * 16 + 4 * lhi + r) * 12 + l15] = acc[r];
        }
    }
    __syncthreads();
    {
        f32x4 y0, y1;
        #pragma unroll
        for (int i = 0; i < 4; i++) { y0[i] = Yl[t * 12 + i]; y1[i] = Yl[t * 12 + 4 + i]; }
        *(f32x4*)(pb + 8 + t * 8)     = y0;
        *(f32x4*)(pb + 8 + t * 8 + 4) = y1;
    }
}

// ---------------------------------------------------------------------------
// K_red: stage-1 reduction. grid 256 (8b x 32 groups), each sums 4 tiles.
__global__ __launch_bounds__(256) void k_red(const float* __restrict__ part,
                                             float* __restrict__ part2) {
    int blk = blockIdx.x, t = threadIdx.x;
    int base = blk * 4;
    float acc[8] = {};
    float accS = 0.f;
    #pragma unroll
    for (int g = 0; g < 4; g++) {
        const float* pb = part + (size_t)(base + g) * 2056;
        #pragma unroll
        for (int i = 0; i < 8; i++) acc[i] += pb[8 + 256 * i + t];
        if (t < 8) accS += pb[t];
    }
    float* ob = part2 + (size_t)blk * 2056;
    if (t < 8) ob[t] = accS;
    #pragma unroll
    for (int i = 0; i < 8; i++) ob[8 + 256 * i + t] = acc[i];
}

// ---------------------------------------------------------------------------
// K_comb: per b: reduce 32 groups -> Y,S ; hd = Wv.y/S + bv via MFMA. grid 8.
__global__ __launch_bounds__(256) void k_comb(const float* __restrict__ part2,
                                              const unsigned short* __restrict__ Wcb,
                                              const float* __restrict__ bcv,
                                              float* __restrict__ hdg) {
    int b = blockIdx.x, t = threadIdx.x;
    __shared__ float Yt[8][260];
    __shared__ float S[8];
    const float* pbase = part2 + (size_t)b * 32 * 2056;
    float acc[8] = {};
    float accS = 0.f;
    #pragma unroll 8
    for (int g = 0; g < 32; g++) {
        const float* pb = pbase + (size_t)g * 2056;
        #pragma unroll
        for (int i = 0; i < 8; i++) acc[i] += pb[8 + 256 * i + t];
        if (t < 8) accS += pb[t];
    }
    #pragma unroll
    for (int i = 0; i < 8; i++) {
        int e = 256 * i + t;
        Yt[e & 7][e >> 3] = acc[i];
    }
    if (t < 8) S[t] = accS;
    __syncthreads();

    int w = t >> 6, lane = t & 63, l15 = lane & 15, lhi = lane >> 4;
    float invS = 1.0f / S[l15 & 7];
    #pragma unroll
    for (int mf = 0; mf < 4; mf++) {
        int f = w * 4 + mf;
        f32x4 acc4 = {};
        for (int kk = 0; kk < 8; kk++) {
            bf16x8 aw = *(const bf16x8*)(Wcb + (size_t)(256 + f * 16 + l15) * 256 + kk * 32 + 8 * lhi);
            f32x4 y0 = *(const f32x4*)&Yt[l15 & 7][kk * 32 + 8 * lhi];
            f32x4 y1 = *(const f32x4*)&Yt[l15 & 7][kk * 32 + 8 * lhi + 4];
            bf16x8 by;
            #pragma unroll
            for (int i = 0; i < 4; i++) { by[i] = (short)f2b(y0[i]); by[4 + i] = (short)f2b(y1[i]); }
            acc4 = __builtin_amdgcn_mfma_f32_16x16x32_bf16(aw, by, acc4, 0, 0, 0);
        }
        if (l15 == (f >> 1)) {
            #pragma unroll
            for (int r = 0; r < 4; r++) {
                int row = f * 16 + 4 * lhi + r;
                hdg[b * 256 + row] = acc4[r] * invS + bcv[256 + row];
            }
        }
    }
}

// ---------------------------------------------------------------------------
// K_vec2: 1 block x 256.
__global__ __launch_bounds__(256) void k_vec2(const unsigned short* __restrict__ WF,
                                              const float* __restrict__ hdg,
                                              const float* __restrict__ mean_low,
                                              const float* __restrict__ ext_out_b,
                                              const float* __restrict__ gate_ext_b,
                                              float* __restrict__ ext_vec,
                                              float* __restrict__ ext_gate) {
    __shared__ unsigned short xA[16][264];
    __shared__ unsigned short xB[16][264];
    __shared__ unsigned short xC[16][264];
    int t = threadIdx.x;
    int w = t >> 6, lane = t & 63, l15 = lane & 15, lhi = lane >> 4;
    const unsigned short* WoF    = WF + 278528;
    const unsigned short* WgeLoF = WF + 344064;
    const unsigned short* WgeHiF = WF + 409600;
    {
        int bb = t >> 5, kb = t & 31;
        #pragma unroll
        for (int q = 0; q < 4; q++) {
            int k0 = (kb + 32 * q) * 2;
            *(unsigned int*)&xA[bb][k0] =
                (unsigned int)f2b(hdg[bb * 256 + k0]) | ((unsigned int)f2b(hdg[bb * 256 + k0 + 1]) << 16);
            *(unsigned int*)&xB[bb][k0] =
                (unsigned int)f2b(mean_low[bb * 256 + k0]) | ((unsigned int)f2b(mean_low[bb * 256 + k0 + 1]) << 16);
        }
    }
    __syncthreads();
    {
        f32x4 acc[4] = {};
        for (int kk = 0; kk < 8; kk++) {
            bf16x8 a = *(const bf16x8*)&xA[l15][kk * 32 + 8 * lhi];
            #pragma unroll
            for (int ni = 0; ni < 4; ni++) {
                int ct = w * 4 + ni;
                bf16x8 bfr = *(const bf16x8*)(WoF + ((size_t)(ct * 8 + kk) << 9) + lane * 8);
                acc[ni] = __builtin_amdgcn_mfma_f32_16x16x32_bf16(a, bfr, acc[ni], 0, 0, 0);
            }
        }
        if (lhi < 2) {
            #pragma unroll
            for (int ni = 0; ni < 4; ni++) {
                int c = w * 64 + ni * 16 + l15;
                float bb = ext_out_b[c];
                #pragma unroll
                for (int r = 0; r < 4; r++) {
                    int b = 4 * lhi + r;
                    float val = acc[ni][r] + bb;
                    ext_vec[b * 256 + c] = val;
                    xC[b][c] = f2b(val);
                }
            }
        }
    }
    __syncthreads();
    {
        f32x4 acc[4] = {};
        for (int kk = 0; kk < 8; kk++) {
            bf16x8 a = *(const bf16x8*)&xB[l15][kk * 32 + 8 * lhi];
            #pragma unroll
            for (int ni = 0; ni < 4; ni++) {
                int ct = w * 4 + ni;
                bf16x8 bfr = *(const bf16x8*)(WgeLoF + ((size_t)(ct * 8 + kk) << 9) + lane * 8);
                acc[ni] = __builtin_amdgcn_mfma_f32_16x16x32_bf16(a, bfr, acc[ni], 0, 0, 0);
            }
        }
        for (int kk = 0; kk < 8; kk++) {
            bf16x8 a = *(const bf16x8*)&xC[l15][kk * 32 + 8 * lhi];
            #pragma unroll
            for (int ni = 0; ni < 4; ni++) {
                int ct = w * 4 + ni;
                bf16x8 bfr = *(const bf16x8*)(WgeHiF + ((size_t)(ct * 8 + kk) << 9) + lane * 8);
                acc[ni] = __builtin_amdgcn_mfma_f32_16x16x32_bf16(a, bfr, acc[ni], 0, 0, 0);
            }
        }
        if (lhi < 2) {
            #pragma unroll
            for (int ni = 0; ni < 4; ni++) {
                int c = w * 64 + ni * 16 + l15;
                float bb = gate_ext_b[c];
                #pragma unroll
                for (int r = 0; r < 4; r++) {
                    int b = 4 * lhi + r;
                    ext_gate[b * 256 + c] = 1.0f / (1.0f + expf(-(acc[ni][r] + bb)));
                }
            }
        }
    }
}

// ---------------------------------------------------------------------------
// K5: ext_final
__global__ __launch_bounds__(256) void k_ext_final(const float* __restrict__ low,
                                                   const float* __restrict__ ext_vec,
                                                   const float* __restrict__ ext_gate,
                                                   float* __restrict__ out) {
    int idx = blockIdx.x * 256 + threadIdx.x;
    #pragma unroll
    for (int rep = 0; rep < 4; ++rep) {
        int i = idx + rep * 524288;
        int bc = i >> 10;
        float g = ext_gate[bc];
        float vv = ext_vec[bc];
        f32x4 L = *(const f32x4*)(low + (size_t)i * 4);
        f32x4 o;
        #pragma unroll
        for (int c = 0; c < 4; c++) o[c] = L[c] + g * (vv - L[c]);
        *(f32x4*)(out + (size_t)i * 4) = o;
    }
}

// ---------------------------------------------------------------------------
// K6: road gate GEMM + elementwise. 32-px tiles, grid 1024, 512 thr.
__global__ __launch_bounds__(512) void k_road(const float* __restrict__ high,
                                              const unsigned short* __restrict__ W3b,
                                              const float* __restrict__ rg_const,
                                              const float* __restrict__ road_vec,
                                              float* __restrict__ outbuf) {
    __shared__ float Xs[32 * 256];
    char* Xc = (char*)Xs;
    int bid = blockIdx.x;
    int b  = bid >> 7;
    int p0 = (bid & 127) << 5;
    int t  = threadIdx.x;
    const float* hb = high + (size_t)b * 1048576;

    int w = t >> 6, lane = t & 63, l15 = lane & 15, lhi = lane >> 4;
    // prefetch epilogue scalars early (hide latency under staging + GEMM)
    float rc[2], rv[2];
    #pragma unroll
    for (int ni = 0; ni < 2; ni++) {
        int o = w * 32 + ni * 16 + l15;
        rc[ni] = rg_const[b * 256 + o];
        rv[ni] = road_vec[b * 256 + o];
    }

    int c0 = t >> 3;
    int j4 = (t & 7) * 4;
    #pragma unroll
    for (int it = 0; it < 4; ++it) {
        int c = c0 + 64 * it;
        f32x4 g = *(const f32x4*)(hb + (size_t)c * 4096 + p0 + j4);
        #pragma unroll
        for (int i = 0; i < 4; i++) {
            int j = j4 + i;
            *(float*)(Xc + ((j * 1024 + 4 * c) ^ ((j & 15) << 4))) = g[i];
        }
    }
    __syncthreads();

    f32x4 acc[2][2] = {};
    for (int kk = 0; kk < 8; kk++) {
        bf16x8 a[2];
        #pragma unroll
        for (int mi = 0; mi < 2; mi++) {
            int j = mi * 16 + l15;
            int base = j * 1024 + (kk * 32 + 8 * lhi) * 4;
            int sw = (j & 15) << 4;
            f32x4 x0 = *(const f32x4*)(Xc + (base ^ sw));
            f32x4 x1 = *(const f32x4*)(Xc + ((base + 16) ^ sw));
            bf16x8 av;
            #pragma unroll
            for (int i = 0; i < 4; i++) {
                av[i]     = (short)f2b(x0[i]);
                av[4 + i] = (short)f2b(x1[i]);
            }
            a[mi] = av;
        }
        #pragma unroll
        for (int ni = 0; ni < 2; ni++) {
            int o = w * 32 + ni * 16 + l15;
            bf16x8 bf = *(const bf16x8*)(W3b + (size_t)o * 256 + kk * 32 + 8 * lhi);
            acc[0][ni] = __builtin_amdgcn_mfma_f32_16x16x32_bf16(a[0], bf, acc[0][ni], 0, 0, 0);
            acc[1][ni] = __builtin_amdgcn_mfma_f32_16x16x32_bf16(a[1], bf, acc[1][ni], 0, 0, 0);
        }
    }
    __syncthreads();

    #pragma unroll
    for (int ni = 0; ni < 2; ni++) {
        int o = w * 32 + ni * 16 + l15;
        #pragma unroll
        for (int mi = 0; mi < 2; mi++)
            #pragma unroll
            for (int r = 0; r < 4; r++) {
                int j = mi * 16 + 4 * lhi + r;
                float* slot = (float*)(Xc + ((j * 1024 + 4 * o) ^ ((j & 15) << 4)));
                float z = acc[mi][ni][r] + rc[ni];
                float gte = 1.0f / (1.0f + expf(-z));
                float hv = *slot;
                *slot = hv + gte * (rv[ni] - hv);
            }
    }
    __syncthreads();

    float* ob = outbuf + 8388608 + (size_t)b * 1048576;
    #pragma unroll
    for (int it = 0; it < 4; ++it) {
        int c = c0 + 64 * it;
        f32x4 o4;
        #pragma unroll
        for (int i = 0; i < 4; i++) {
            int j = j4 + i;
            o4[i] = *(const float*)(Xc + ((j * 1024 + 4 * c) ^ ((j & 15) << 4)));
        }
        *(f32x4*)(ob + (size_t)c * 4096 + p0 + j4) = o4;
    }
}

// ---------------------------------------------------------------------------
extern "C" void kernel_launch(void* const* d_in, const int* in_sizes, int n_in,
                              void* d_out, int out_size, void* d_ws, size_t ws_size,
                              hipStream_t stream) {
    const float* low         = (const float*)d_in[0];
    const float* high        = (const float*)d_in[1];
    const float* ext_context = (const float*)d_in[2];
    const float* road_feat   = (const float*)d_in[3];
    const float* ext_proj_w  = (const float*)d_in[4];
    const float* ext_proj_b  = (const float*)d_in[5];
    const float* road_proj_w = (const float*)d_in[6];
    const float* road_proj_b = (const float*)d_in[7];
    const float* ext_qkv_w   = (const float*)d_in[8];
    const float* ext_qkv_b   = (const float*)d_in[9];
    const float* road_qkv_w  = (const float*)d_in[10];
    const float* road_qkv_b  = (const float*)d_in[11];
    const float* ext_out_w   = (const float*)d_in[12];
    const float* ext_out_b   = (const float*)d_in[13];
    const float* road_out_w  = (const float*)d_in[14];
    const float* road_out_b  = (const float*)d_in[15];
    const float* gate_ext_w  = (const float*)d_in[16];
    const float* gate_ext_b  = (const float*)d_in[17];
    const float* gate_road_w = (const float*)d_in[18];
    const float* gate_road_b = (const float*)d_in[19];

    float* out = (float*)d_out;
    unsigned short* wsb = (unsigned short*)d_ws;
    unsigned short* Wcb = wsb;               // [0, 131072)
    unsigned short* W3b = wsb + 131072;      // [131072, 196608)
    float* fw = (float*)((char*)d_ws + 983040);
    float* ext_q    = fw;
    float* road_vec = fw + 2048;
    float* rg_const = fw + 4096;
    float* ext_vec  = fw + 8192;
    float* ext_gate = fw + 10240;
    float* mean_low = fw + 12288;
    float* bcv      = fw + 14336;
    float* hdg      = fw + 16384;
    float* cqs      = fw + 18432;
    unsigned short* wqf = (unsigned short*)(fw + 18496);
    float* part  = out + 2097152;            // 1024*2056
    float* part2 = out + 4718592;            // 256*2056 = 526,336, ends 5,244,928
    unsigned short* WF = (unsigned short*)(out + 5505024);

    k_setup<<<2496, 256, 0, stream>>>(road_proj_w, road_qkv_w, road_proj_b, road_qkv_b,
                                      gate_road_w, ext_proj_w, ext_qkv_w, road_out_w,
                                      ext_out_w, gate_ext_w, low,
                                      W3b, Wcb, WF, bcv, mean_low);
    k_tiny<<<1, 256, 0, stream>>>(WF, ext_context, ext_proj_b, ext_qkv_b,
                                  road_out_b, gate_road_b, ext_q, road_vec, rg_const);
    k_qfold<<<8, 256, 0, stream>>>(Wcb, bcv, ext_q, wqf, cqs);
    k_att<<<1024, 256, 0, stream>>>(road_feat, wqf, cqs, part);
    k_red<<<256, 256, 0, stream>>>(part, part2);
    k_comb<<<8, 256, 0, stream>>>(part2, Wcb, bcv, hdg);
    k_vec2<<<1, 256, 0, stream>>>(WF, hdg, mean_low, ext_out_b, gate_ext_b,
                                  ext_vec, ext_gate);
    k_ext_final<<<2048, 256, 0, stream>>>(low, ext_vec, ext_gate, out);
    k_road<<<1024, 512, 0, stream>>>(high, W3b, rg_const, road_vec, out);
}

// Round 21
// 148.172 us; speedup vs baseline: 1.0305x; 1.0305x over previous
//
#include <hip/hip_runtime.h>

typedef short bf16x8 __attribute__((ext_vector_type(8)));
typedef float f32x4 __attribute__((ext_vector_type(4)));

#define ATT_SCALE 0.17677669529663687f

__device__ __forceinline__ unsigned short f2b(float f) {
    unsigned int u = __builtin_bit_cast(unsigned int, f);
    unsigned int r = u + 0x7FFFu + ((u >> 16) & 1u);
    return (unsigned short)(r >> 16);
}
__device__ __forceinline__ float b2f(unsigned short v) {
    return __builtin_bit_cast(float, (unsigned int)v << 16);
}
__device__ __forceinline__ float wsum64(float v) {
    #pragma unroll
    for (int m = 32; m; m >>= 1) v += __shfl_xor(v, m, 64);
    return v;
}

// WF fragment offsets (ushorts): Wq 0, Wv 65536, Wro 131072, Wg2 196608,
// Wp 262144, Wo 278528, WgeLo 344064, WgeHi 409600. total 475136.

// ---------------------------------------------------------------------------
// K_setup: all parallel prep. grid 2496 x 256.
__global__ __launch_bounds__(256) void k_setup(const float* __restrict__ w1,
                                               const float* __restrict__ wqkv,
                                               const float* __restrict__ b1,
                                               const float* __restrict__ bqkv,
                                               const float* __restrict__ gate_road_w,
                                               const float* __restrict__ ext_proj_w,
                                               const float* __restrict__ ext_qkv_w,
                                               const float* __restrict__ road_out_w,
                                               const float* __restrict__ ext_out_w,
                                               const float* __restrict__ gate_ext_w,
                                               const float* __restrict__ low,
                                               unsigned short* __restrict__ W3b,
                                               unsigned short* __restrict__ Wcb,
                                               unsigned short* __restrict__ WF,
                                               float* __restrict__ bcv,
                                               float* __restrict__ mean_low) {
    int bid = blockIdx.x, t = threadIdx.x;
    __shared__ float sel[8][256];
    __shared__ float red[8][4];
    if (bid >= 448) {
        int bc = bid - 448;
        const f32x4* p4 = (const f32x4*)(low + (size_t)bc * 4096);
        float s = 0.f;
        for (int i = t; i < 1024; i += 256) {
            f32x4 v = p4[i];
            s += v[0] + v[1] + v[2] + v[3];
        }
        s = wsum64(s);
        if ((t & 63) == 0) red[0][t >> 6] = s;
        __syncthreads();
        if (t == 0) mean_low[bc] = (red[0][0] + red[0][1] + red[0][2] + red[0][3]) * (1.0f / 4096.0f);
    } else if (bid < 256) {
        int i = bid * 256 + t;
        int o = i >> 8, k = i & 255;
        W3b[i] = f2b(gate_road_w[o * 512 + k]);
    } else if (bid < 320) {
        int o0 = (bid - 256) * 8;
        #pragma unroll
        for (int r = 0; r < 8; r++) {
            int o = o0 + r;
            int c = (o < 256) ? o : o - 256;
            int g = (o < 256) ? 1 : 2;
            sel[r][t] = wqkv[(size_t)(3 * c + g) * 256 + t];
        }
        __syncthreads();
        float b1v = b1[t];
        #pragma unroll
        for (int r = 0; r < 8; r++) {
            float v = wsum64(sel[r][t] * b1v);
            if ((t & 63) == 0) red[r][t >> 6] = v;
        }
        __syncthreads();
        if (t < 8) {
            int o = o0 + t;
            int c = (o < 256) ? o : o - 256;
            int g = (o < 256) ? 1 : 2;
            bcv[o] = red[t][0] + red[t][1] + red[t][2] + red[t][3] + bqkv[3 * c + g];
        }
        float acc[8] = {};
        #pragma unroll 16
        for (int m = 0; m < 256; m++) {
            float w1v = w1[(size_t)m * 256 + t];
            #pragma unroll
            for (int r = 0; r < 8; r++) acc[r] += sel[r][m] * w1v;
        }
        #pragma unroll
        for (int r = 0; r < 8; r++) Wcb[(size_t)(o0 + r) * 256 + t] = f2b(acc[r]);
    } else {
        int mb = bid - 320;
        int m = mb >> 4, ctile = mb & 15;
        const float* src;
        int stride, K, coff;
        unsigned short* dst;
        switch (m) {
        case 0: src = ext_qkv_w;                     stride = 256; K = 256; coff = 0;   dst = WF;          break;
        case 1: src = ext_qkv_w + (size_t)512 * 256; stride = 256; K = 256; coff = 0;   dst = WF + 65536;  break;
        case 2: src = road_out_w;                    stride = 256; K = 256; coff = 0;   dst = WF + 131072; break;
        case 3: src = gate_road_w;                   stride = 512; K = 256; coff = 256; dst = WF + 196608; break;
        case 4: src = ext_proj_w;                    stride = 64;  K = 64;  coff = 0;   dst = WF + 262144; break;
        case 5: src = ext_out_w;                     stride = 256; K = 256; coff = 0;   dst = WF + 278528; break;
        case 6: src = gate_ext_w;                    stride = 512; K = 256; coff = 0;   dst = WF + 344064; break;
        default: src = gate_ext_w;                   stride = 512; K = 256; coff = 256; dst = WF + 409600; break;
        }
        int lc = t >> 4, kseg = t & 15;
        int k0 = kseg * 16;
        if (k0 < K) {
            int c = ctile * 16 + lc;
            const float* sp = src + (size_t)c * stride + coff + k0;
            f32x4 v0 = *(const f32x4*)sp;
            f32x4 v1 = *(const f32x4*)(sp + 4);
            f32x4 v2 = *(const f32x4*)(sp + 8);
            f32x4 v3 = *(const f32x4*)(sp + 12);
            int kk = kseg >> 1;
            int Kt = K >> 5;
            #pragma unroll
            for (int h = 0; h < 2; h++) {
                int lhi = (kseg & 1) * 2 + h;
                int lane = lhi * 16 + lc;
                bf16x8 o;
                f32x4 a = h ? v2 : v0, b = h ? v3 : v1;
                #pragma unroll
                for (int i = 0; i < 4; i++) { o[i] = (short)f2b(a[i]); o[4 + i] = (short)f2b(b[i]); }
                *(bf16x8*)(dst + ((size_t)(ctile * Kt + kk) << 9) + lane * 8) = o;
            }
        }
    }
}

// ---------------------------------------------------------------------------
// K_tiny: 4-hop vector chain via MFMA, 1 block x 256.
__global__ __launch_bounds__(256) void k_tiny(const unsigned short* __restrict__ WF,
                                              const float* __restrict__ ext_context,
                                              const float* __restrict__ ext_proj_b,
                                              const float* __restrict__ ext_qkv_b,
                                              const float* __restrict__ road_out_b,
                                              const float* __restrict__ gate_road_b,
                                              float* __restrict__ ext_q,
                                              float* __restrict__ road_vec,
                                              float* __restrict__ rg_const) {
    __shared__ unsigned short xA[16][264];
    __shared__ unsigned short xB[16][264];
    int t = threadIdx.x;
    int w = t >> 6, lane = t & 63, l15 = lane & 15, lhi = lane >> 4;
    const unsigned short* WqF  = WF;
    const unsigned short* WvF  = WF + 65536;
    const unsigned short* WroF = WF + 131072;
    const unsigned short* WgF  = WF + 196608;
    const unsigned short* WpF  = WF + 262144;
    {
        int b = t >> 5, k0 = (t & 31) * 2;
        float c0v = ext_context[b * 64 + k0];
        float c1v = ext_context[b * 64 + k0 + 1];
        *(unsigned int*)&xA[b][k0] = (unsigned int)f2b(c0v) | ((unsigned int)f2b(c1v) << 16);
    }
    __syncthreads();
    {
        f32x4 acc[4] = {};
        #pragma unroll
        for (int kk = 0; kk < 2; kk++) {
            bf16x8 a = *(const bf16x8*)&xA[l15][kk * 32 + 8 * lhi];
            #pragma unroll
            for (int ni = 0; ni < 4; ni++) {
                int ct = w * 4 + ni;
                bf16x8 bfr = *(const bf16x8*)(WpF + ((size_t)(ct * 2 + kk) << 9) + lane * 8);
                acc[ni] = __builtin_amdgcn_mfma_f32_16x16x32_bf16(a, bfr, acc[ni], 0, 0, 0);
            }
        }
        if (lhi < 2) {
            #pragma unroll
            for (int ni = 0; ni < 4; ni++) {
                int c = w * 64 + ni * 16 + l15;
                float bp = ext_proj_b[c];
                #pragma unroll
                for (int r = 0; r < 4; r++)
                    xB[4 * lhi + r][c] = f2b(acc[ni][r] + bp);
            }
        }
    }
    __syncthreads();
    {
        f32x4 acc[8] = {};
        bool isq = (w < 2);
        int cbase = (w & 1) * 128;
        const unsigned short* Wb = isq ? WqF : WvF;
        for (int kk = 0; kk < 8; kk++) {
            bf16x8 a = *(const bf16x8*)&xB[l15][kk * 32 + 8 * lhi];
            #pragma unroll
            for (int ni = 0; ni < 8; ni++) {
                int ct = (cbase >> 4) + ni;
                bf16x8 bfr = *(const bf16x8*)(Wb + ((size_t)(ct * 8 + kk) << 9) + lane * 8);
                acc[ni] = __builtin_amdgcn_mfma_f32_16x16x32_bf16(a, bfr, acc[ni], 0, 0, 0);
            }
        }
        if (lhi < 2) {
            #pragma unroll
            for (int ni = 0; ni < 8; ni++) {
                int c = cbase + ni * 16 + l15;
                float bb = ext_qkv_b[(isq ? 0 : 512) + c];
                #pragma unroll
                for (int r = 0; r < 4; r++) {
                    int b = 4 * lhi + r;
                    float val = acc[ni][r] + bb;
                    if (isq) ext_q[b * 256 + c] = val;
                    else     xA[b][c] = f2b(val);
                }
            }
        }
    }
    __syncthreads();
    {
        f32x4 acc[4] = {};
        for (int kk = 0; kk < 8; kk++) {
            bf16x8 a = *(const bf16x8*)&xA[l15][kk * 32 + 8 * lhi];
            #pragma unroll
            for (int ni = 0; ni < 4; ni++) {
                int ct = w * 4 + ni;
                bf16x8 bfr = *(const bf16x8*)(WroF + ((size_t)(ct * 8 + kk) << 9) + lane * 8);
                acc[ni] = __builtin_amdgcn_mfma_f32_16x16x32_bf16(a, bfr, acc[ni], 0, 0, 0);
            }
        }
        if (lhi < 2) {
            #pragma unroll
            for (int ni = 0; ni < 4; ni++) {
                int c = w * 64 + ni * 16 + l15;
                float bb = road_out_b[c];
                #pragma unroll
                for (int r = 0; r < 4; r++) {
                    int b = 4 * lhi + r;
                    float val = acc[ni][r] + bb;
                    road_vec[b * 256 + c] = val;
                    xB[b][c] = f2b(val);
                }
            }
        }
    }
    __syncthreads();
    {
        f32x4 acc[4] = {};
        for (int kk = 0; kk < 8; kk++) {
            bf16x8 a = *(const bf16x8*)&xB[l15][kk * 32 + 8 * lhi];
            #pragma unroll
            for (int ni = 0; ni < 4; ni++) {
                int ct = w * 4 + ni;
                bf16x8 bfr = *(const bf16x8*)(WgF + ((size_t)(ct * 8 + kk) << 9) + lane * 8);
                acc[ni] = __builtin_amdgcn_mfma_f32_16x16x32_bf16(a, bfr, acc[ni], 0, 0, 0);
            }
        }
        if (lhi < 2) {
            #pragma unroll
            for (int ni = 0; ni < 4; ni++) {
                int c = w * 64 + ni * 16 + l15;
                float bb = gate_road_b[c];
                #pragma unroll
                for (int r = 0; r < 4; r++)
                    rg_const[(4 * lhi + r) * 256 + c] = acc[ni][r] + bb;
            }
        }
    }
}

// ---------------------------------------------------------------------------
// K_qfold: wq[b,h,:] = sum_d q[b,h,d]*Wc_k[h*32+d,:]  -> fragment-major bf16.
__global__ __launch_bounds__(256) void k_qfold(const unsigned short* __restrict__ Wcb,
                                               const float* __restrict__ bcv,
                                               const float* __restrict__ ext_q,
                                               unsigned short* __restrict__ wqf,
                                               float* __restrict__ cqs) {
    int b = blockIdx.x, t = threadIdx.x;
    __shared__ float qs[256];
    __shared__ float wq[8][256];
    qs[t] = ext_q[b * 256 + t];
    __syncthreads();
    float acc[8] = {};
    #pragma unroll
    for (int h = 0; h < 8; h++)
        #pragma unroll 8
        for (int d = 0; d < 32; d++)
            acc[h] += qs[h * 32 + d] * b2f(Wcb[(size_t)(h * 32 + d) * 256 + t]);
    #pragma unroll
    for (int h = 0; h < 8; h++) wq[h][t] = acc[h];
    if (t < 8) {
        float s = 0.f;
        #pragma unroll 8
        for (int d = 0; d < 32; d++) s += qs[t * 32 + d] * bcv[t * 32 + d];
        cqs[b * 8 + t] = s * ATT_SCALE;
    }
    __syncthreads();
    #pragma unroll
    for (int q2 = 0; q2 < 2; q2++) {
        int idx = t + 256 * q2;
        int kk = idx >> 6, l = idx & 63;
        int row = l & 15;
        int kb = kk * 32 + (l >> 4) * 8;
        bf16x8 o;
        #pragma unroll
        for (int e = 0; e < 8; e++)
            o[e] = (row < 8) ? (short)f2b(wq[row][kb + e]) : (short)0;
        *(bf16x8*)(wqf + ((size_t)(b * 8 + kk) * 64 + l) * 8) = o;
    }
}

// ---------------------------------------------------------------------------
// K_att: folded attention pass. grid 1024 (8b x 128 tiles of 32px), 256 thr.
__global__ __launch_bounds__(256) void k_att(const float* __restrict__ road_feat,
                                             const unsigned short* __restrict__ wqf,
                                             const float* __restrict__ cqs,
                                             float* __restrict__ part) {
    __shared__ __align__(16) char u_smem[32 * 256 * 2];   // 16 KB: Xs, later Yl
    __shared__ unsigned short Xt[256][40];                // [ch][px] bf16
    __shared__ float es_[8][36];
    char* Xc = u_smem;
    float* Yl = (float*)u_smem;
    int bid = blockIdx.x;
    int b  = bid >> 7;
    int p0 = (bid & 127) << 5;
    int t  = threadIdx.x;
    const float* rfb = road_feat + (size_t)b * 1048576;

    int c0 = 2 * (t >> 3);
    int j4 = (t & 7) * 4;
    #pragma unroll
    for (int it = 0; it < 4; ++it) {
        int c = c0 + 64 * it;
        f32x4 g0 = *(const f32x4*)(rfb + (size_t)c * 4096 + p0 + j4);
        f32x4 g1 = *(const f32x4*)(rfb + (size_t)(c + 1) * 4096 + p0 + j4);
        unsigned short h0[4], h1[4];
        #pragma unroll
        for (int i = 0; i < 4; i++) { h0[i] = f2b(g0[i]); h1[i] = f2b(g1[i]); }
        #pragma unroll
        for (int i = 0; i < 4; i++) {
            int j = j4 + i;
            unsigned int pk = (unsigned int)h0[i] | ((unsigned int)h1[i] << 16);
            *(unsigned int*)(Xc + ((j * 512 + 2 * c) ^ ((j & 15) << 4))) = pk;
        }
        *(unsigned int*)&Xt[c][j4]         = (unsigned int)h0[0] | ((unsigned int)h0[1] << 16);
        *(unsigned int*)&Xt[c][j4 + 2]     = (unsigned int)h0[2] | ((unsigned int)h0[3] << 16);
        *(unsigned int*)&Xt[c + 1][j4]     = (unsigned int)h1[0] | ((unsigned int)h1[1] << 16);
        *(unsigned int*)&Xt[c + 1][j4 + 2] = (unsigned int)h1[2] | ((unsigned int)h1[3] << 16);
    }
    __syncthreads();

    int w = t >> 6, lane = t & 63, l15 = lane & 15, lhi = lane >> 4;

    if (w < 2) {
        f32x4 acc = {};
        int px = w * 16 + l15;
        for (int kk = 0; kk < 8; kk++) {
            bf16x8 aq = *(const bf16x8*)(wqf + ((size_t)(b * 8 + kk) * 64 + lane) * 8);
            bf16x8 bx = *(const bf16x8*)(Xc + ((px * 512 + (kk * 32 + 8 * lhi) * 2) ^ ((px & 15) << 4)));
            acc = __builtin_amdgcn_mfma_f32_16x16x32_bf16(aq, bx, acc, 0, 0, 0);
        }
        #pragma unroll
        for (int r = 0; r < 4; r++) {
            int row = 4 * lhi + r;
            if (row < 8)
                es_[row][w * 16 + l15] = expf(acc[r] * ATT_SCALE + cqs[b * 8 + row]);
        }
    }
    __syncthreads();   // Xs reads done; u_smem may now be reused as Yl

    float* pb = part + (size_t)bid * 2056;
    {
        float v = es_[t >> 5][t & 31];
        v += __shfl_xor(v, 1, 64);
        v += __shfl_xor(v, 2, 64);
        v += __shfl_xor(v, 4, 64);
        v += __shfl_xor(v, 8, 64);
        v += __shfl_xor(v, 16, 64);
        if ((lane & 31) == 0) pb[t >> 5] = v;
    }
    bf16x8 besv;
    {
        f32x4 e0 = *(const f32x4*)&es_[l15 & 7][8 * lhi];
        f32x4 e1 = *(const f32x4*)&es_[l15 & 7][8 * lhi + 4];
        #pragma unroll
        for (int i = 0; i < 4; i++) { besv[i] = (short)f2b(e0[i]); besv[4 + i] = (short)f2b(e1[i]); }
    }
    #pragma unroll
    for (int mf = 0; mf < 4; mf++) {
        int f = w * 4 + mf;
        int c = f * 16 + l15;
        bf16x8 ax = *(const bf16x8*)&Xt[c][8 * lhi];
        f32x4 acc = {};
        acc = __builtin_amdgcn_mfma_f32_16x16x32_bf16(ax, besv, acc, 0, 0, 0);
        if (l15 < 8) {
            #pragma unroll
            for (int r = 0; r < 4; r++)
                Yl[(f * 16 + 4 * lhi + r) * 12 + l15] = acc[r];
        }
    }
    __syncthreads();
    {
        f32x4 y0, y1;
        #pragma unroll
        for (int i = 0; i < 4; i++) { y0[i] = Yl[t * 12 + i]; y1[i] = Yl[t * 12 + 4 + i]; }
        *(f32x4*)(pb + 8 + t * 8)     = y0;
        *(f32x4*)(pb + 8 + t * 8 + 4) = y1;
    }
}

// ---------------------------------------------------------------------------
// K_red: stage-1 reduction. grid 128 (8b x 16 groups), each sums 8 tiles.
__global__ __launch_bounds__(256) void k_red(const float* __restrict__ part,
                                             float* __restrict__ part2) {
    int blk = blockIdx.x, t = threadIdx.x;
    int base = blk * 8;
    float acc[8] = {};
    float accS = 0.f;
    #pragma unroll
    for (int g = 0; g < 8; g++) {
        const float* pb = part + (size_t)(base + g) * 2056;
        #pragma unroll
        for (int i = 0; i < 8; i++) acc[i] += pb[8 + 256 * i + t];
        if (t < 8) accS += pb[t];
    }
    float* ob = part2 + (size_t)blk * 2056;
    if (t < 8) ob[t] = accS;
    #pragma unroll
    for (int i = 0; i < 8; i++) ob[8 + 256 * i + t] = acc[i];
}

// ---------------------------------------------------------------------------
// K_comb: per b: reduce 16 groups -> Y,S ; hd = Wv.y/S + bv via MFMA. grid 8.
__global__ __launch_bounds__(256) void k_comb(const float* __restrict__ part2,
                                              const unsigned short* __restrict__ Wcb,
                                              const float* __restrict__ bcv,
                                              float* __restrict__ hdg) {
    int b = blockIdx.x, t = threadIdx.x;
    __shared__ float Yt[8][260];
    __shared__ float S[8];
    const float* pbase = part2 + (size_t)b * 16 * 2056;
    float acc[8] = {};
    float accS = 0.f;
    #pragma unroll 4
    for (int g = 0; g < 16; g++) {
        const float* pb = pbase + (size_t)g * 2056;
        #pragma unroll
        for (int i = 0; i < 8; i++) acc[i] += pb[8 + 256 * i + t];
        if (t < 8) accS += pb[t];
    }
    #pragma unroll
    for (int i = 0; i < 8; i++) {
        int e = 256 * i + t;
        Yt[e & 7][e >> 3] = acc[i];
    }
    if (t < 8) S[t] = accS;
    __syncthreads();

    int w = t >> 6, lane = t & 63, l15 = lane & 15, lhi = lane >> 4;
    float invS = 1.0f / S[l15 & 7];
    #pragma unroll
    for (int mf = 0; mf < 4; mf++) {
        int f = w * 4 + mf;
        f32x4 acc4 = {};
        for (int kk = 0; kk < 8; kk++) {
            bf16x8 aw = *(const bf16x8*)(Wcb + (size_t)(256 + f * 16 + l15) * 256 + kk * 32 + 8 * lhi);
            f32x4 y0 = *(const f32x4*)&Yt[l15 & 7][kk * 32 + 8 * lhi];
            f32x4 y1 = *(const f32x4*)&Yt[l15 & 7][kk * 32 + 8 * lhi + 4];
            bf16x8 by;
            #pragma unroll
            for (int i = 0; i < 4; i++) { by[i] = (short)f2b(y0[i]); by[4 + i] = (short)f2b(y1[i]); }
            acc4 = __builtin_amdgcn_mfma_f32_16x16x32_bf16(aw, by, acc4, 0, 0, 0);
        }
        if (l15 == (f >> 1)) {
            #pragma unroll
            for (int r = 0; r < 4; r++) {
                int row = f * 16 + 4 * lhi + r;
                hdg[b * 256 + row] = acc4[r] * invS + bcv[256 + row];
            }
        }
    }
}

// ---------------------------------------------------------------------------
// K_vec2: 1 block x 256.
__global__ __launch_bounds__(256) void k_vec2(const unsigned short* __restrict__ WF,
                                              const float* __restrict__ hdg,
                                              const float* __restrict__ mean_low,
                                              const float* __restrict__ ext_out_b,
                                              const float* __restrict__ gate_ext_b,
                                              float* __restrict__ ext_vec,
                                              float* __restrict__ ext_gate) {
    __shared__ unsigned short xA[16][264];
    __shared__ unsigned short xB[16][264];
    __shared__ unsigned short xC[16][264];
    int t = threadIdx.x;
    int w = t >> 6, lane = t & 63, l15 = lane & 15, lhi = lane >> 4;
    const unsigned short* WoF    = WF + 278528;
    const unsigned short* WgeLoF = WF + 344064;
    const unsigned short* WgeHiF = WF + 409600;
    {
        int bb = t >> 5, kb = t & 31;
        #pragma unroll
        for (int q = 0; q < 4; q++) {
            int k0 = (kb + 32 * q) * 2;
            *(unsigned int*)&xA[bb][k0] =
                (unsigned int)f2b(hdg[bb * 256 + k0]) | ((unsigned int)f2b(hdg[bb * 256 + k0 + 1]) << 16);
            *(unsigned int*)&xB[bb][k0] =
                (unsigned int)f2b(mean_low[bb * 256 + k0]) | ((unsigned int)f2b(mean_low[bb * 256 + k0 + 1]) << 16);
        }
    }
    __syncthreads();
    {
        f32x4 acc[4] = {};
        for (int kk = 0; kk < 8; kk++) {
            bf16x8 a = *(const bf16x8*)&xA[l15][kk * 32 + 8 * lhi];
            #pragma unroll
            for (int ni = 0; ni < 4; ni++) {
                int ct = w * 4 + ni;
                bf16x8 bfr = *(const bf16x8*)(WoF + ((size_t)(ct * 8 + kk) << 9) + lane * 8);
                acc[ni] = __builtin_amdgcn_mfma_f32_16x16x32_bf16(a, bfr, acc[ni], 0, 0, 0);
            }
        }
        if (lhi < 2) {
            #pragma unroll
            for (int ni = 0; ni < 4; ni++) {
                int c = w * 64 + ni * 16 + l15;
                float bb = ext_out_b[c];
                #pragma unroll
                for (int r = 0; r < 4; r++) {
                    int b = 4 * lhi + r;
                    float val = acc[ni][r] + bb;
                    ext_vec[b * 256 + c] = val;
                    xC[b][c] = f2b(val);
                }
            }
        }
    }
    __syncthreads();
    {
        f32x4 acc[4] = {};
        for (int kk = 0; kk < 8; kk++) {
            bf16x8 a = *(const bf16x8*)&xB[l15][kk * 32 + 8 * lhi];
            #pragma unroll
            for (int ni = 0; ni < 4; ni++) {
                int ct = w * 4 + ni;
                bf16x8 bfr = *(const bf16x8*)(WgeLoF + ((size_t)(ct * 8 + kk) << 9) + lane * 8);
                acc[ni] = __builtin_amdgcn_mfma_f32_16x16x32_bf16(a, bfr, acc[ni], 0, 0, 0);
            }
        }
        for (int kk = 0; kk < 8; kk++) {
            bf16x8 a = *(const bf16x8*)&xC[l15][kk * 32 + 8 * lhi];
            #pragma unroll
            for (int ni = 0; ni < 4; ni++) {
                int ct = w * 4 + ni;
                bf16x8 bfr = *(const bf16x8*)(WgeHiF + ((size_t)(ct * 8 + kk) << 9) + lane * 8);
                acc[ni] = __builtin_amdgcn_mfma_f32_16x16x32_bf16(a, bfr, acc[ni], 0, 0, 0);
            }
        }
        if (lhi < 2) {
            #pragma unroll
            for (int ni = 0; ni < 4; ni++) {
                int c = w * 64 + ni * 16 + l15;
                float bb = gate_ext_b[c];
                #pragma unroll
                for (int r = 0; r < 4; r++) {
                    int b = 4 * lhi + r;
                    ext_gate[b * 256 + c] = 1.0f / (1.0f + expf(-(acc[ni][r] + bb)));
                }
            }
        }
    }
}

// ---------------------------------------------------------------------------
// K5: ext_final
__global__ __launch_bounds__(256) void k_ext_final(const float* __restrict__ low,
                                                   const float* __restrict__ ext_vec,
                                                   const float* __restrict__ ext_gate,
                                                   float* __restrict__ out) {
    int idx = blockIdx.x * 256 + threadIdx.x;
    #pragma unroll
    for (int rep = 0; rep < 4; ++rep) {
        int i = idx + rep * 524288;
        int bc = i >> 10;
        float g = ext_gate[bc];
        float vv = ext_vec[bc];
        f32x4 L = *(const f32x4*)(low + (size_t)i * 4);
        f32x4 o;
        #pragma unroll
        for (int c = 0; c < 4; c++) o[c] = L[c] + g * (vv - L[c]);
        *(f32x4*)(out + (size_t)i * 4) = o;
    }
}

// ---------------------------------------------------------------------------
// K6: road gate GEMM + elementwise. 32-px tiles, grid 1024, 512 thr.
__global__ __launch_bounds__(512) void k_road(const float* __restrict__ high,
                                              const unsigned short* __restrict__ W3b,
                                              const float* __restrict__ rg_const,
                                              const float* __restrict__ road_vec,
                                              float* __restrict__ outbuf) {
    __shared__ float Xs[32 * 256];
    char* Xc = (char*)Xs;
    int bid = blockIdx.x;
    int b  = bid >> 7;
    int p0 = (bid & 127) << 5;
    int t  = threadIdx.x;
    const float* hb = high + (size_t)b * 1048576;

    int c0 = t >> 3;
    int j4 = (t & 7) * 4;
    #pragma unroll
    for (int it = 0; it < 4; ++it) {
        int c = c0 + 64 * it;
        f32x4 g = *(const f32x4*)(hb + (size_t)c * 4096 + p0 + j4);
        #pragma unroll
        for (int i = 0; i < 4; i++) {
            int j = j4 + i;
            *(float*)(Xc + ((j * 1024 + 4 * c) ^ ((j & 15) << 4))) = g[i];
        }
    }
    __syncthreads();

    int w = t >> 6, lane = t & 63, l15 = lane & 15, lhi = lane >> 4;
    f32x4 acc[2][2] = {};
    for (int kk = 0; kk < 8; kk++) {
        bf16x8 a[2];
        #pragma unroll
        for (int mi = 0; mi < 2; mi++) {
            int j = mi * 16 + l15;
            int base = j * 1024 + (kk * 32 + 8 * lhi) * 4;
            int sw = (j & 15) << 4;
            f32x4 x0 = *(const f32x4*)(Xc + (base ^ sw));
            f32x4 x1 = *(const f32x4*)(Xc + ((base + 16) ^ sw));
            bf16x8 av;
            #pragma unroll
            for (int i = 0; i < 4; i++) {
                av[i]     = (short)f2b(x0[i]);
                av[4 + i] = (short)f2b(x1[i]);
            }
            a[mi] = av;
        }
        #pragma unroll
        for (int ni = 0; ni < 2; ni++) {
            int o = w * 32 + ni * 16 + l15;
            bf16x8 bf = *(const bf16x8*)(W3b + (size_t)o * 256 + kk * 32 + 8 * lhi);
            acc[0][ni] = __builtin_amdgcn_mfma_f32_16x16x32_bf16(a[0], bf, acc[0][ni], 0, 0, 0);
            acc[1][ni] = __builtin_amdgcn_mfma_f32_16x16x32_bf16(a[1], bf, acc[1][ni], 0, 0, 0);
        }
    }
    __syncthreads();

    #pragma unroll
    for (int ni = 0; ni < 2; ni++) {
        int o = w * 32 + ni * 16 + l15;
        float rc = rg_const[b * 256 + o];
        float rv = road_vec[b * 256 + o];
        #pragma unroll
        for (int mi = 0; mi < 2; mi++)
            #pragma unroll
            for (int r = 0; r < 4; r++) {
                int j = mi * 16 + 4 * lhi + r;
                float* slot = (float*)(Xc + ((j * 1024 + 4 * o) ^ ((j & 15) << 4)));
                float z = acc[mi][ni][r] + rc;
                float gte = 1.0f / (1.0f + expf(-z));
                float hv = *slot;
                *slot = hv + gte * (rv - hv);
            }
    }
    __syncthreads();

    float* ob = outbuf + 8388608 + (size_t)b * 1048576;
    #pragma unroll
    for (int it = 0; it < 4; ++it) {
        int c = c0 + 64 * it;
        f32x4 o4;
        #pragma unroll
        for (int i = 0; i < 4; i++) {
            int j = j4 + i;
            o4[i] = *(const float*)(Xc + ((j * 1024 + 4 * c) ^ ((j & 15) << 4)));
        }
        *(f32x4*)(ob + (size_t)c * 4096 + p0 + j4) = o4;
    }
}

// ---------------------------------------------------------------------------
extern "C" void kernel_launch(void* const* d_in, const int* in_sizes, int n_in,
                              void* d_out, int out_size, void* d_ws, size_t ws_size,
                              hipStream_t stream) {
    const float* low         = (const float*)d_in[0];
    const float* high        = (const float*)d_in[1];
    const float* ext_context = (const float*)d_in[2];
    const float* road_feat   = (const float*)d_in[3];
    const float* ext_proj_w  = (const float*)d_in[4];
    const float* ext_proj_b  = (const float*)d_in[5];
    const float* road_proj_w = (const float*)d_in[6];
    const float* road_proj_b = (const float*)d_in[7];
    const float* ext_qkv_w   = (const float*)d_in[8];
    const float* ext_qkv_b   = (const float*)d_in[9];
    const float* road_qkv_w  = (const float*)d_in[10];
    const float* road_qkv_b  = (const float*)d_in[11];
    const float* ext_out_w   = (const float*)d_in[12];
    const float* ext_out_b   = (const float*)d_in[13];
    const float* road_out_w  = (const float*)d_in[14];
    const float* road_out_b  = (const float*)d_in[15];
    const float* gate_ext_w  = (const float*)d_in[16];
    const float* gate_ext_b  = (const float*)d_in[17];
    const float* gate_road_w = (const float*)d_in[18];
    const float* gate_road_b = (const float*)d_in[19];

    float* out = (float*)d_out;
    unsigned short* wsb = (unsigned short*)d_ws;
    unsigned short* Wcb = wsb;               // [0, 131072)
    unsigned short* W3b = wsb + 131072;      // [131072, 196608)
    float* fw = (float*)((char*)d_ws + 983040);
    float* ext_q    = fw;
    float* road_vec = fw + 2048;
    float* rg_const = fw + 4096;
    float* ext_vec  = fw + 8192;
    float* ext_gate = fw + 10240;
    float* mean_low = fw + 12288;
    float* bcv      = fw + 14336;
    float* hdg      = fw + 16384;
    float* cqs      = fw + 18432;
    unsigned short* wqf = (unsigned short*)(fw + 18496);
    float* part  = out + 2097152;            // 1024*2056
    float* part2 = out + 4718592;            // 128*2056
    unsigned short* WF = (unsigned short*)(out + 5242880);

    k_setup<<<2496, 256, 0, stream>>>(road_proj_w, road_qkv_w, road_proj_b, road_qkv_b,
                                      gate_road_w, ext_proj_w, ext_qkv_w, road_out_w,
                                      ext_out_w, gate_ext_w, low,
                                      W3b, Wcb, WF, bcv, mean_low);
    k_tiny<<<1, 256, 0, stream>>>(WF, ext_context, ext_proj_b, ext_qkv_b,
                                  road_out_b, gate_road_b, ext_q, road_vec, rg_const);
    k_qfold<<<8, 256, 0, stream>>>(Wcb, bcv, ext_q, wqf, cqs);
    k_att<<<1024, 256, 0, stream>>>(road_feat, wqf, cqs, part);
    k_red<<<128, 256, 0, stream>>>(part, part2);
    k_comb<<<8, 256, 0, stream>>>(part2, Wcb, bcv, hdg);
    k_vec2<<<1, 256, 0, stream>>>(WF, hdg, mean_low, ext_out_b, gate_ext_b,
                                  ext_vec, ext_gate);
    k_ext_final<<<2048, 256, 0, stream>>>(low, ext_vec, ext_gate, out);
    k_road<<<1024, 512, 0, stream>>>(high, W3b, rg_const, road_vec, out);
}

// Round 22
// 147.768 us; speedup vs baseline: 1.0333x; 1.0027x over previous
//
#include <hip/hip_runtime.h>

typedef short bf16x8 __attribute__((ext_vector_type(8)));
typedef float f32x4 __attribute__((ext_vector_type(4)));

#define ATT_SCALE 0.17677669529663687f

__device__ __forceinline__ unsigned short f2b(float f) {
    unsigned int u = __builtin_bit_cast(unsigned int, f);
    unsigned int r = u + 0x7FFFu + ((u >> 16) & 1u);
    return (unsigned short)(r >> 16);
}
__device__ __forceinline__ float b2f(unsigned short v) {
    return __builtin_bit_cast(float, (unsigned int)v << 16);
}
__device__ __forceinline__ float wsum64(float v) {
    #pragma unroll
    for (int m = 32; m; m >>= 1) v += __shfl_xor(v, m, 64);
    return v;
}

// WF fragment offsets (ushorts): Wq 0, Wv 65536, Wro 131072, Wg2 196608,
// Wp 262144, Wo 278528, WgeLo 344064, WgeHi 409600. total 475136.

// ---------------------------------------------------------------------------
// K_setup: all parallel prep. grid 2496 x 256.
__global__ __launch_bounds__(256) void k_setup(const float* __restrict__ w1,
                                               const float* __restrict__ wqkv,
                                               const float* __restrict__ b1,
                                               const float* __restrict__ bqkv,
                                               const float* __restrict__ gate_road_w,
                                               const float* __restrict__ ext_proj_w,
                                               const float* __restrict__ ext_qkv_w,
                                               const float* __restrict__ road_out_w,
                                               const float* __restrict__ ext_out_w,
                                               const float* __restrict__ gate_ext_w,
                                               const float* __restrict__ low,
                                               unsigned short* __restrict__ W3b,
                                               unsigned short* __restrict__ Wcb,
                                               unsigned short* __restrict__ WF,
                                               float* __restrict__ bcv,
                                               float* __restrict__ mean_low) {
    int bid = blockIdx.x, t = threadIdx.x;
    __shared__ float sel[8][256];
    __shared__ float red[8][4];
    if (bid >= 448) {
        int bc = bid - 448;
        const f32x4* p4 = (const f32x4*)(low + (size_t)bc * 4096);
        float s = 0.f;
        for (int i = t; i < 1024; i += 256) {
            f32x4 v = p4[i];
            s += v[0] + v[1] + v[2] + v[3];
        }
        s = wsum64(s);
        if ((t & 63) == 0) red[0][t >> 6] = s;
        __syncthreads();
        if (t == 0) mean_low[bc] = (red[0][0] + red[0][1] + red[0][2] + red[0][3]) * (1.0f / 4096.0f);
    } else if (bid < 256) {
        int i = bid * 256 + t;
        int o = i >> 8, k = i & 255;
        W3b[i] = f2b(gate_road_w[o * 512 + k]);
    } else if (bid < 320) {
        int o0 = (bid - 256) * 8;
        #pragma unroll
        for (int r = 0; r < 8; r++) {
            int o = o0 + r;
            int c = (o < 256) ? o : o - 256;
            int g = (o < 256) ? 1 : 2;
            sel[r][t] = wqkv[(size_t)(3 * c + g) * 256 + t];
        }
        __syncthreads();
        float b1v = b1[t];
        #pragma unroll
        for (int r = 0; r < 8; r++) {
            float v = wsum64(sel[r][t] * b1v);
            if ((t & 63) == 0) red[r][t >> 6] = v;
        }
        __syncthreads();
        if (t < 8) {
            int o = o0 + t;
            int c = (o < 256) ? o : o - 256;
            int g = (o < 256) ? 1 : 2;
            bcv[o] = red[t][0] + red[t][1] + red[t][2] + red[t][3] + bqkv[3 * c + g];
        }
        float acc[8] = {};
        #pragma unroll 16
        for (int m = 0; m < 256; m++) {
            float w1v = w1[(size_t)m * 256 + t];
            #pragma unroll
            for (int r = 0; r < 8; r++) acc[r] += sel[r][m] * w1v;
        }
        #pragma unroll
        for (int r = 0; r < 8; r++) Wcb[(size_t)(o0 + r) * 256 + t] = f2b(acc[r]);
    } else {
        int mb = bid - 320;
        int m = mb >> 4, ctile = mb & 15;
        const float* src;
        int stride, K, coff;
        unsigned short* dst;
        switch (m) {
        case 0: src = ext_qkv_w;                     stride = 256; K = 256; coff = 0;   dst = WF;          break;
        case 1: src = ext_qkv_w + (size_t)512 * 256; stride = 256; K = 256; coff = 0;   dst = WF + 65536;  break;
        case 2: src = road_out_w;                    stride = 256; K = 256; coff = 0;   dst = WF + 131072; break;
        case 3: src = gate_road_w;                   stride = 512; K = 256; coff = 256; dst = WF + 196608; break;
        case 4: src = ext_proj_w;                    stride = 64;  K = 64;  coff = 0;   dst = WF + 262144; break;
        case 5: src = ext_out_w;                     stride = 256; K = 256; coff = 0;   dst = WF + 278528; break;
        case 6: src = gate_ext_w;                    stride = 512; K = 256; coff = 0;   dst = WF + 344064; break;
        default: src = gate_ext_w;                   stride = 512; K = 256; coff = 256; dst = WF + 409600; break;
        }
        int lc = t >> 4, kseg = t & 15;
        int k0 = kseg * 16;
        if (k0 < K) {
            int c = ctile * 16 + lc;
            const float* sp = src + (size_t)c * stride + coff + k0;
            f32x4 v0 = *(const f32x4*)sp;
            f32x4 v1 = *(const f32x4*)(sp + 4);
            f32x4 v2 = *(const f32x4*)(sp + 8);
            f32x4 v3 = *(const f32x4*)(sp + 12);
            int kk = kseg >> 1;
            int Kt = K >> 5;
            #pragma unroll
            for (int h = 0; h < 2; h++) {
                int lhi = (kseg & 1) * 2 + h;
                int lane = lhi * 16 + lc;
                bf16x8 o;
                f32x4 a = h ? v2 : v0, b = h ? v3 : v1;
                #pragma unroll
                for (int i = 0; i < 4; i++) { o[i] = (short)f2b(a[i]); o[4 + i] = (short)f2b(b[i]); }
                *(bf16x8*)(dst + ((size_t)(ctile * Kt + kk) << 9) + lane * 8) = o;
            }
        }
    }
}

// ---------------------------------------------------------------------------
// K_tiny: 4-hop vector chain via MFMA, 1 block x 256.
__global__ __launch_bounds__(256) void k_tiny(const unsigned short* __restrict__ WF,
                                              const float* __restrict__ ext_context,
                                              const float* __restrict__ ext_proj_b,
                                              const float* __restrict__ ext_qkv_b,
                                              const float* __restrict__ road_out_b,
                                              const float* __restrict__ gate_road_b,
                                              float* __restrict__ ext_q,
                                              float* __restrict__ road_vec,
                                              float* __restrict__ rg_const) {
    __shared__ unsigned short xA[16][264];
    __shared__ unsigned short xB[16][264];
    int t = threadIdx.x;
    int w = t >> 6, lane = t & 63, l15 = lane & 15, lhi = lane >> 4;
    const unsigned short* WqF  = WF;
    const unsigned short* WvF  = WF + 65536;
    const unsigned short* WroF = WF + 131072;
    const unsigned short* WgF  = WF + 196608;
    const unsigned short* WpF  = WF + 262144;
    {
        int b = t >> 5, k0 = (t & 31) * 2;
        float c0v = ext_context[b * 64 + k0];
        float c1v = ext_context[b * 64 + k0 + 1];
        *(unsigned int*)&xA[b][k0] = (unsigned int)f2b(c0v) | ((unsigned int)f2b(c1v) << 16);
    }
    __syncthreads();
    {
        f32x4 acc[4] = {};
        #pragma unroll
        for (int kk = 0; kk < 2; kk++) {
            bf16x8 a = *(const bf16x8*)&xA[l15][kk * 32 + 8 * lhi];
            #pragma unroll
            for (int ni = 0; ni < 4; ni++) {
                int ct = w * 4 + ni;
                bf16x8 bfr = *(const bf16x8*)(WpF + ((size_t)(ct * 2 + kk) << 9) + lane * 8);
                acc[ni] = __builtin_amdgcn_mfma_f32_16x16x32_bf16(a, bfr, acc[ni], 0, 0, 0);
            }
        }
        if (lhi < 2) {
            #pragma unroll
            for (int ni = 0; ni < 4; ni++) {
                int c = w * 64 + ni * 16 + l15;
                float bp = ext_proj_b[c];
                #pragma unroll
                for (int r = 0; r < 4; r++)
                    xB[4 * lhi + r][c] = f2b(acc[ni][r] + bp);
            }
        }
    }
    __syncthreads();
    {
        f32x4 acc[8] = {};
        bool isq = (w < 2);
        int cbase = (w & 1) * 128;
        const unsigned short* Wb = isq ? WqF : WvF;
        for (int kk = 0; kk < 8; kk++) {
            bf16x8 a = *(const bf16x8*)&xB[l15][kk * 32 + 8 * lhi];
            #pragma unroll
            for (int ni = 0; ni < 8; ni++) {
                int ct = (cbase >> 4) + ni;
                bf16x8 bfr = *(const bf16x8*)(Wb + ((size_t)(ct * 8 + kk) << 9) + lane * 8);
                acc[ni] = __builtin_amdgcn_mfma_f32_16x16x32_bf16(a, bfr, acc[ni], 0, 0, 0);
            }
        }
        if (lhi < 2) {
            #pragma unroll
            for (int ni = 0; ni < 8; ni++) {
                int c = cbase + ni * 16 + l15;
                float bb = ext_qkv_b[(isq ? 0 : 512) + c];
                #pragma unroll
                for (int r = 0; r < 4; r++) {
                    int b = 4 * lhi + r;
                    float val = acc[ni][r] + bb;
                    if (isq) ext_q[b * 256 + c] = val;
                    else     xA[b][c] = f2b(val);
                }
            }
        }
    }
    __syncthreads();
    {
        f32x4 acc[4] = {};
        for (int kk = 0; kk < 8; kk++) {
            bf16x8 a = *(const bf16x8*)&xA[l15][kk * 32 + 8 * lhi];
            #pragma unroll
            for (int ni = 0; ni < 4; ni++) {
                int ct = w * 4 + ni;
                bf16x8 bfr = *(const bf16x8*)(WroF + ((size_t)(ct * 8 + kk) << 9) + lane * 8);
                acc[ni] = __builtin_amdgcn_mfma_f32_16x16x32_bf16(a, bfr, acc[ni], 0, 0, 0);
            }
        }
        if (lhi < 2) {
            #pragma unroll
            for (int ni = 0; ni < 4; ni++) {
                int c = w * 64 + ni * 16 + l15;
                float bb = road_out_b[c];
                #pragma unroll
                for (int r = 0; r < 4; r++) {
                    int b = 4 * lhi + r;
                    float val = acc[ni][r] + bb;
                    road_vec[b * 256 + c] = val;
                    xB[b][c] = f2b(val);
                }
            }
        }
    }
    __syncthreads();
    {
        f32x4 acc[4] = {};
        for (int kk = 0; kk < 8; kk++) {
            bf16x8 a = *(const bf16x8*)&xB[l15][kk * 32 + 8 * lhi];
            #pragma unroll
            for (int ni = 0; ni < 4; ni++) {
                int ct = w * 4 + ni;
                bf16x8 bfr = *(const bf16x8*)(WgF + ((size_t)(ct * 8 + kk) << 9) + lane * 8);
                acc[ni] = __builtin_amdgcn_mfma_f32_16x16x32_bf16(a, bfr, acc[ni], 0, 0, 0);
            }
        }
        if (lhi < 2) {
            #pragma unroll
            for (int ni = 0; ni < 4; ni++) {
                int c = w * 64 + ni * 16 + l15;
                float bb = gate_road_b[c];
                #pragma unroll
                for (int r = 0; r < 4; r++)
                    rg_const[(4 * lhi + r) * 256 + c] = acc[ni][r] + bb;
            }
        }
    }
}

// ---------------------------------------------------------------------------
// K_qfold: wq[b,h,:] = sum_d q[b,h,d]*Wc_k[h*32+d,:]  -> fragment-major bf16.
__global__ __launch_bounds__(256) void k_qfold(const unsigned short* __restrict__ Wcb,
                                               const float* __restrict__ bcv,
                                               const float* __restrict__ ext_q,
                                               unsigned short* __restrict__ wqf,
                                               float* __restrict__ cqs) {
    int b = blockIdx.x, t = threadIdx.x;
    __shared__ float qs[256];
    __shared__ float wq[8][256];
    qs[t] = ext_q[b * 256 + t];
    __syncthreads();
    float acc[8] = {};
    #pragma unroll
    for (int h = 0; h < 8; h++)
        #pragma unroll 8
        for (int d = 0; d < 32; d++)
            acc[h] += qs[h * 32 + d] * b2f(Wcb[(size_t)(h * 32 + d) * 256 + t]);
    #pragma unroll
    for (int h = 0; h < 8; h++) wq[h][t] = acc[h];
    if (t < 8) {
        float s = 0.f;
        #pragma unroll 8
        for (int d = 0; d < 32; d++) s += qs[t * 32 + d] * bcv[t * 32 + d];
        cqs[b * 8 + t] = s * ATT_SCALE;
    }
    __syncthreads();
    #pragma unroll
    for (int q2 = 0; q2 < 2; q2++) {
        int idx = t + 256 * q2;
        int kk = idx >> 6, l = idx & 63;
        int row = l & 15;
        int kb = kk * 32 + (l >> 4) * 8;
        bf16x8 o;
        #pragma unroll
        for (int e = 0; e < 8; e++)
            o[e] = (row < 8) ? (short)f2b(wq[row][kb + e]) : (short)0;
        *(bf16x8*)(wqf + ((size_t)(b * 8 + kk) * 64 + l) * 8) = o;
    }
}

// ---------------------------------------------------------------------------
// K_att: folded attention pass. grid 1024 (8b x 128 tiles of 32px), 256 thr.
__global__ __launch_bounds__(256) void k_att(const float* __restrict__ road_feat,
                                             const unsigned short* __restrict__ wqf,
                                             const float* __restrict__ cqs,
                                             float* __restrict__ part) {
    __shared__ __align__(16) char u_smem[32 * 256 * 2];   // 16 KB: Xs, later Yl
    __shared__ unsigned short Xt[256][40];                // [ch][px] bf16
    __shared__ float es_[8][36];
    char* Xc = u_smem;
    float* Yl = (float*)u_smem;
    int bid = blockIdx.x;
    int b  = bid >> 7;
    int p0 = (bid & 127) << 5;
    int t  = threadIdx.x;
    const float* rfb = road_feat + (size_t)b * 1048576;

    int c0 = 2 * (t >> 3);
    int j4 = (t & 7) * 4;
    #pragma unroll
    for (int it = 0; it < 4; ++it) {
        int c = c0 + 64 * it;
        f32x4 g0 = *(const f32x4*)(rfb + (size_t)c * 4096 + p0 + j4);
        f32x4 g1 = *(const f32x4*)(rfb + (size_t)(c + 1) * 4096 + p0 + j4);
        unsigned short h0[4], h1[4];
        #pragma unroll
        for (int i = 0; i < 4; i++) { h0[i] = f2b(g0[i]); h1[i] = f2b(g1[i]); }
        #pragma unroll
        for (int i = 0; i < 4; i++) {
            int j = j4 + i;
            unsigned int pk = (unsigned int)h0[i] | ((unsigned int)h1[i] << 16);
            *(unsigned int*)(Xc + ((j * 512 + 2 * c) ^ ((j & 15) << 4))) = pk;
        }
        *(unsigned int*)&Xt[c][j4]         = (unsigned int)h0[0] | ((unsigned int)h0[1] << 16);
        *(unsigned int*)&Xt[c][j4 + 2]     = (unsigned int)h0[2] | ((unsigned int)h0[3] << 16);
        *(unsigned int*)&Xt[c + 1][j4]     = (unsigned int)h1[0] | ((unsigned int)h1[1] << 16);
        *(unsigned int*)&Xt[c + 1][j4 + 2] = (unsigned int)h1[2] | ((unsigned int)h1[3] << 16);
    }
    __syncthreads();

    int w = t >> 6, lane = t & 63, l15 = lane & 15, lhi = lane >> 4;

    if (w < 2) {
        f32x4 acc = {};
        int px = w * 16 + l15;
        for (int kk = 0; kk < 8; kk++) {
            bf16x8 aq = *(const bf16x8*)(wqf + ((size_t)(b * 8 + kk) * 64 + lane) * 8);
            bf16x8 bx = *(const bf16x8*)(Xc + ((px * 512 + (kk * 32 + 8 * lhi) * 2) ^ ((px & 15) << 4)));
            acc = __builtin_amdgcn_mfma_f32_16x16x32_bf16(aq, bx, acc, 0, 0, 0);
        }
        #pragma unroll
        for (int r = 0; r < 4; r++) {
            int row = 4 * lhi + r;
            if (row < 8)
                es_[row][w * 16 + l15] = expf(acc[r] * ATT_SCALE + cqs[b * 8 + row]);
        }
    }
    __syncthreads();   // Xs reads done; u_smem may now be reused as Yl

    float* pb = part + (size_t)bid * 2056;
    {
        float v = es_[t >> 5][t & 31];
        v += __shfl_xor(v, 1, 64);
        v += __shfl_xor(v, 2, 64);
        v += __shfl_xor(v, 4, 64);
        v += __shfl_xor(v, 8, 64);
        v += __shfl_xor(v, 16, 64);
        if ((lane & 31) == 0) pb[t >> 5] = v;
    }
    bf16x8 besv;
    {
        f32x4 e0 = *(const f32x4*)&es_[l15 & 7][8 * lhi];
        f32x4 e1 = *(const f32x4*)&es_[l15 & 7][8 * lhi + 4];
        #pragma unroll
        for (int i = 0; i < 4; i++) { besv[i] = (short)f2b(e0[i]); besv[4 + i] = (short)f2b(e1[i]); }
    }
    #pragma unroll
    for (int mf = 0; mf < 4; mf++) {
        int f = w * 4 + mf;
        int c = f * 16 + l15;
        bf16x8 ax = *(const bf16x8*)&Xt[c][8 * lhi];
        f32x4 acc = {};
        acc = __builtin_amdgcn_mfma_f32_16x16x32_bf16(ax, besv, acc, 0, 0, 0);
        if (l15 < 8) {
            #pragma unroll
            for (int r = 0; r < 4; r++)
                Yl[(f * 16 + 4 * lhi + r) * 12 + l15] = acc[r];
        }
    }
    __syncthreads();
    {
        f32x4 y0, y1;
        #pragma unroll
        for (int i = 0; i < 4; i++) { y0[i] = Yl[t * 12 + i]; y1[i] = Yl[t * 12 + 4 + i]; }
        *(f32x4*)(pb + 8 + t * 8)     = y0;
        *(f32x4*)(pb + 8 + t * 8 + 4) = y1;
    }
}

// ---------------------------------------------------------------------------
// K_red: stage-1 reduction. grid 128 (8b x 16 groups), each sums 8 tiles.
__global__ __launch_bounds__(256) void k_red(const float* __restrict__ part,
                                             float* __restrict__ part2) {
    int blk = blockIdx.x, t = threadIdx.x;
    int base = blk * 8;
    float acc[8] = {};
    float accS = 0.f;
    #pragma unroll
    for (int g = 0; g < 8; g++) {
        const float* pb = part + (size_t)(base + g) * 2056;
        #pragma unroll
        for (int i = 0; i < 8; i++) acc[i] += pb[8 + 256 * i + t];
        if (t < 8) accS += pb[t];
    }
    float* ob = part2 + (size_t)blk * 2056;
    if (t < 8) ob[t] = accS;
    #pragma unroll
    for (int i = 0; i < 8; i++) ob[8 + 256 * i + t] = acc[i];
}

// ---------------------------------------------------------------------------
// K_comb: per b: reduce 16 groups -> Y,S ; hd = Wv.y/S + bv via MFMA. grid 8.
__global__ __launch_bounds__(256) void k_comb(const float* __restrict__ part2,
                                              const unsigned short* __restrict__ Wcb,
                                              const float* __restrict__ bcv,
                                              float* __restrict__ hdg) {
    int b = blockIdx.x, t = threadIdx.x;
    __shared__ float Yt[8][260];
    __shared__ float S[8];
    const float* pbase = part2 + (size_t)b * 16 * 2056;
    float acc[8] = {};
    float accS = 0.f;
    #pragma unroll 4
    for (int g = 0; g < 16; g++) {
        const float* pb = pbase + (size_t)g * 2056;
        #pragma unroll
        for (int i = 0; i < 8; i++) acc[i] += pb[8 + 256 * i + t];
        if (t < 8) accS += pb[t];
    }
    #pragma unroll
    for (int i = 0; i < 8; i++) {
        int e = 256 * i + t;
        Yt[e & 7][e >> 3] = acc[i];
    }
    if (t < 8) S[t] = accS;
    __syncthreads();

    int w = t >> 6, lane = t & 63, l15 = lane & 15, lhi = lane >> 4;
    float invS = 1.0f / S[l15 & 7];
    #pragma unroll
    for (int mf = 0; mf < 4; mf++) {
        int f = w * 4 + mf;
        f32x4 acc4 = {};
        for (int kk = 0; kk < 8; kk++) {
            bf16x8 aw = *(const bf16x8*)(Wcb + (size_t)(256 + f * 16 + l15) * 256 + kk * 32 + 8 * lhi);
            f32x4 y0 = *(const f32x4*)&Yt[l15 & 7][kk * 32 + 8 * lhi];
            f32x4 y1 = *(const f32x4*)&Yt[l15 & 7][kk * 32 + 8 * lhi + 4];
            bf16x8 by;
            #pragma unroll
            for (int i = 0; i < 4; i++) { by[i] = (short)f2b(y0[i]); by[4 + i] = (short)f2b(y1[i]); }
            acc4 = __builtin_amdgcn_mfma_f32_16x16x32_bf16(aw, by, acc4, 0, 0, 0);
        }
        if (l15 == (f >> 1)) {
            #pragma unroll
            for (int r = 0; r < 4; r++) {
                int row = f * 16 + 4 * lhi + r;
                hdg[b * 256 + row] = acc4[r] * invS + bcv[256 + row];
            }
        }
    }
}

// ---------------------------------------------------------------------------
// K_vec2: 1 block x 256.
__global__ __launch_bounds__(256) void k_vec2(const unsigned short* __restrict__ WF,
                                              const float* __restrict__ hdg,
                                              const float* __restrict__ mean_low,
                                              const float* __restrict__ ext_out_b,
                                              const float* __restrict__ gate_ext_b,
                                              float* __restrict__ ext_vec,
                                              float* __restrict__ ext_gate) {
    __shared__ unsigned short xA[16][264];
    __shared__ unsigned short xB[16][264];
    __shared__ unsigned short xC[16][264];
    int t = threadIdx.x;
    int w = t >> 6, lane = t & 63, l15 = lane & 15, lhi = lane >> 4;
    const unsigned short* WoF    = WF + 278528;
    const unsigned short* WgeLoF = WF + 344064;
    const unsigned short* WgeHiF = WF + 409600;
    {
        int bb = t >> 5, kb = t & 31;
        #pragma unroll
        for (int q = 0; q < 4; q++) {
            int k0 = (kb + 32 * q) * 2;
            *(unsigned int*)&xA[bb][k0] =
                (unsigned int)f2b(hdg[bb * 256 + k0]) | ((unsigned int)f2b(hdg[bb * 256 + k0 + 1]) << 16);
            *(unsigned int*)&xB[bb][k0] =
                (unsigned int)f2b(mean_low[bb * 256 + k0]) | ((unsigned int)f2b(mean_low[bb * 256 + k0 + 1]) << 16);
        }
    }
    __syncthreads();
    {
        f32x4 acc[4] = {};
        for (int kk = 0; kk < 8; kk++) {
            bf16x8 a = *(const bf16x8*)&xA[l15][kk * 32 + 8 * lhi];
            #pragma unroll
            for (int ni = 0; ni < 4; ni++) {
                int ct = w * 4 + ni;
                bf16x8 bfr = *(const bf16x8*)(WoF + ((size_t)(ct * 8 + kk) << 9) + lane * 8);
                acc[ni] = __builtin_amdgcn_mfma_f32_16x16x32_bf16(a, bfr, acc[ni], 0, 0, 0);
            }
        }
        if (lhi < 2) {
            #pragma unroll
            for (int ni = 0; ni < 4; ni++) {
                int c = w * 64 + ni * 16 + l15;
                float bb = ext_out_b[c];
                #pragma unroll
                for (int r = 0; r < 4; r++) {
                    int b = 4 * lhi + r;
                    float val = acc[ni][r] + bb;
                    ext_vec[b * 256 + c] = val;
                    xC[b][c] = f2b(val);
                }
            }
        }
    }
    __syncthreads();
    {
        f32x4 acc[4] = {};
        for (int kk = 0; kk < 8; kk++) {
            bf16x8 a = *(const bf16x8*)&xB[l15][kk * 32 + 8 * lhi];
            #pragma unroll
            for (int ni = 0; ni < 4; ni++) {
                int ct = w * 4 + ni;
                bf16x8 bfr = *(const bf16x8*)(WgeLoF + ((size_t)(ct * 8 + kk) << 9) + lane * 8);
                acc[ni] = __builtin_amdgcn_mfma_f32_16x16x32_bf16(a, bfr, acc[ni], 0, 0, 0);
            }
        }
        for (int kk = 0; kk < 8; kk++) {
            bf16x8 a = *(const bf16x8*)&xC[l15][kk * 32 + 8 * lhi];
            #pragma unroll
            for (int ni = 0; ni < 4; ni++) {
                int ct = w * 4 + ni;
                bf16x8 bfr = *(const bf16x8*)(WgeHiF + ((size_t)(ct * 8 + kk) << 9) + lane * 8);
                acc[ni] = __builtin_amdgcn_mfma_f32_16x16x32_bf16(a, bfr, acc[ni], 0, 0, 0);
            }
        }
        if (lhi < 2) {
            #pragma unroll
            for (int ni = 0; ni < 4; ni++) {
                int c = w * 64 + ni * 16 + l15;
                float bb = gate_ext_b[c];
                #pragma unroll
                for (int r = 0; r < 4; r++) {
                    int b = 4 * lhi + r;
                    ext_gate[b * 256 + c] = 1.0f / (1.0f + expf(-(acc[ni][r] + bb)));
                }
            }
        }
    }
}

// ---------------------------------------------------------------------------
// K5: ext_final
__global__ __launch_bounds__(256) void k_ext_final(const float* __restrict__ low,
                                                   const float* __restrict__ ext_vec,
                                                   const float* __restrict__ ext_gate,
                                                   float* __restrict__ out) {
    int idx = blockIdx.x * 256 + threadIdx.x;
    #pragma unroll
    for (int rep = 0; rep < 4; ++rep) {
        int i = idx + rep * 524288;
        int bc = i >> 10;
        float g = ext_gate[bc];
        float vv = ext_vec[bc];
        f32x4 L = *(const f32x4*)(low + (size_t)i * 4);
        f32x4 o;
        #pragma unroll
        for (int c = 0; c < 4; c++) o[c] = L[c] + g * (vv - L[c]);
        *(f32x4*)(out + (size_t)i * 4) = o;
    }
}

// ---------------------------------------------------------------------------
// K6: road gate GEMM + elementwise. 32-px tiles, grid 1024, 512 thr.
// Dual-format staging: Xs f32 (epilogue) + Xb bf16 (GEMM) -> f2b once, not 8x.
__global__ __launch_bounds__(512) void k_road(const float* __restrict__ high,
                                              const unsigned short* __restrict__ W3b,
                                              const float* __restrict__ rg_const,
                                              const float* __restrict__ road_vec,
                                              float* __restrict__ outbuf) {
    __shared__ float Xs[32 * 256];            // f32 swizzled (exact high for gate)
    __shared__ unsigned short Xb[32 * 256];   // bf16 swizzled (GEMM operand)
    char* Xc  = (char*)Xs;
    char* Xbc = (char*)Xb;
    int bid = blockIdx.x;
    int b  = bid >> 7;
    int p0 = (bid & 127) << 5;
    int t  = threadIdx.x;
    const float* hb = high + (size_t)b * 1048576;

    // stage: 2 adjacent channels x 4 pixels; write f32 pair + packed bf16 u32
    int c0 = 2 * (t >> 3);
    int j4 = (t & 7) * 4;
    #pragma unroll
    for (int it = 0; it < 2; ++it) {
        int c = c0 + 128 * it;
        f32x4 g0 = *(const f32x4*)(hb + (size_t)c * 4096 + p0 + j4);
        f32x4 g1 = *(const f32x4*)(hb + (size_t)(c + 1) * 4096 + p0 + j4);
        #pragma unroll
        for (int i = 0; i < 4; i++) {
            int j = j4 + i;
            int sw = (j & 15) << 4;
            *(float*)(Xc + ((j * 1024 + 4 * c) ^ sw))       = g0[i];
            *(float*)(Xc + ((j * 1024 + 4 * (c + 1)) ^ sw)) = g1[i];
            unsigned int pk = (unsigned int)f2b(g0[i]) | ((unsigned int)f2b(g1[i]) << 16);
            *(unsigned int*)(Xbc + ((j * 512 + 2 * c) ^ sw)) = pk;
        }
    }
    __syncthreads();

    int w = t >> 6, lane = t & 63, l15 = lane & 15, lhi = lane >> 4;
    f32x4 acc[2][2] = {};
    for (int kk = 0; kk < 8; kk++) {
        bf16x8 a[2];
        #pragma unroll
        for (int mi = 0; mi < 2; mi++) {
            int j = mi * 16 + l15;
            int off = (j * 512 + (kk * 32 + 8 * lhi) * 2) ^ ((j & 15) << 4);
            a[mi] = *(const bf16x8*)(Xbc + off);
        }
        #pragma unroll
        for (int ni = 0; ni < 2; ni++) {
            int o = w * 32 + ni * 16 + l15;
            bf16x8 bf = *(const bf16x8*)(W3b + (size_t)o * 256 + kk * 32 + 8 * lhi);
            acc[0][ni] = __builtin_amdgcn_mfma_f32_16x16x32_bf16(a[0], bf, acc[0][ni], 0, 0, 0);
            acc[1][ni] = __builtin_amdgcn_mfma_f32_16x16x32_bf16(a[1], bf, acc[1][ni], 0, 0, 0);
        }
    }
    __syncthreads();

    #pragma unroll
    for (int ni = 0; ni < 2; ni++) {
        int o = w * 32 + ni * 16 + l15;
        float rc = rg_const[b * 256 + o];
        float rv = road_vec[b * 256 + o];
        #pragma unroll
        for (int mi = 0; mi < 2; mi++)
            #pragma unroll
            for (int r = 0; r < 4; r++) {
                int j = mi * 16 + 4 * lhi + r;
                float* slot = (float*)(Xc + ((j * 1024 + 4 * o) ^ ((j & 15) << 4)));
                float z = acc[mi][ni][r] + rc;
                float gte = 1.0f / (1.0f + expf(-z));
                float hv = *slot;
                *slot = hv + gte * (rv - hv);
            }
    }
    __syncthreads();

    float* ob = outbuf + 8388608 + (size_t)b * 1048576;
    {
        int cs = t >> 3;    // 0..63
        #pragma unroll
        for (int it = 0; it < 4; ++it) {
            int c = cs + 64 * it;
            f32x4 o4;
            #pragma unroll
            for (int i = 0; i < 4; i++) {
                int j = j4 + i;
                o4[i] = *(const float*)(Xc + ((j * 1024 + 4 * c) ^ ((j & 15) << 4)));
            }
            *(f32x4*)(ob + (size_t)c * 4096 + p0 + j4) = o4;
        }
    }
}

// ---------------------------------------------------------------------------
extern "C" void kernel_launch(void* const* d_in, const int* in_sizes, int n_in,
                              void* d_out, int out_size, void* d_ws, size_t ws_size,
                              hipStream_t stream) {
    const float* low         = (const float*)d_in[0];
    const float* high        = (const float*)d_in[1];
    const float* ext_context = (const float*)d_in[2];
    const float* road_feat   = (const float*)d_in[3];
    const float* ext_proj_w  = (const float*)d_in[4];
    const float* ext_proj_b  = (const float*)d_in[5];
    const float* road_proj_w = (const float*)d_in[6];
    const float* road_proj_b = (const float*)d_in[7];
    const float* ext_qkv_w   = (const float*)d_in[8];
    const float* ext_qkv_b   = (const float*)d_in[9];
    const float* road_qkv_w  = (const float*)d_in[10];
    const float* road_qkv_b  = (const float*)d_in[11];
    const float* ext_out_w   = (const float*)d_in[12];
    const float* ext_out_b   = (const float*)d_in[13];
    const float* road_out_w  = (const float*)d_in[14];
    const float* road_out_b  = (const float*)d_in[15];
    const float* gate_ext_w  = (const float*)d_in[16];
    const float* gate_ext_b  = (const float*)d_in[17];
    const float* gate_road_w = (const float*)d_in[18];
    const float* gate_road_b = (const float*)d_in[19];

    float* out = (float*)d_out;
    unsigned short* wsb = (unsigned short*)d_ws;
    unsigned short* Wcb = wsb;               // [0, 131072)
    unsigned short* W3b = wsb + 131072;      // [131072, 196608)
    float* fw = (float*)((char*)d_ws + 983040);
    float* ext_q    = fw;
    float* road_vec = fw + 2048;
    float* rg_const = fw + 4096;
    float* ext_vec  = fw + 8192;
    float* ext_gate = fw + 10240;
    float* mean_low = fw + 12288;
    float* bcv      = fw + 14336;
    float* hdg      = fw + 16384;
    float* cqs      = fw + 18432;
    unsigned short* wqf = (unsigned short*)(fw + 18496);
    float* part  = out + 2097152;            // 1024*2056
    float* part2 = out + 4718592;            // 128*2056
    unsigned short* WF = (unsigned short*)(out + 5242880);

    k_setup<<<2496, 256, 0, stream>>>(road_proj_w, road_qkv_w, road_proj_b, road_qkv_b,
                                      gate_road_w, ext_proj_w, ext_qkv_w, road_out_w,
                                      ext_out_w, gate_ext_w, low,
                                      W3b, Wcb, WF, bcv, mean_low);
    k_tiny<<<1, 256, 0, stream>>>(WF, ext_context, ext_proj_b, ext_qkv_b,
                                  road_out_b, gate_road_b, ext_q, road_vec, rg_const);
    k_qfold<<<8, 256, 0, stream>>>(Wcb, bcv, ext_q, wqf, cqs);
    k_att<<<1024, 256, 0, stream>>>(road_feat, wqf, cqs, part);
    k_red<<<128, 256, 0, stream>>>(part, part2);
    k_comb<<<8, 256, 0, stream>>>(part2, Wcb, bcv, hdg);
    k_vec2<<<1, 256, 0, stream>>>(WF, hdg, mean_low, ext_out_b, gate_ext_b,
                                  ext_vec, ext_gate);
    k_ext_final<<<2048, 256, 0, stream>>>(low, ext_vec, ext_gate, out);
    k_road<<<1024, 512, 0, stream>>>(high, W3b, rg_const, road_vec, out);
}